// Round 7
// baseline (584.467 us; speedup 1.0000x reference)
//
#include <hip/hip_runtime.h>
#include <hip/hip_bf16.h>

typedef __hip_bfloat16 bf16;
typedef float f4v __attribute__((ext_vector_type(4)));
typedef short s8v __attribute__((ext_vector_type(8)));

#define CSD    384
#define LL     1024
#define NH     8
#define BL     4096        // B*L
#define NPROJ  1920
#define QDP    96          // 80 real ext-Q/K dims, padded to 96
#define VDP    160         // 152 real ext-V dims, padded to 160
#define FEATD  1280

// ---- fp32 input mirror (z1/z2 NOT mirrored — read raw in assemble) ----
#define OFF_S      0
#define OFF_QUAT   1572864
#define OFF_TRANS  1589248
#define OFF_MASK   1601536
#define OFF_BPOST  1605632
#define OFF_BRES   1605648
#define OFF_WPOST  1605664
#define OFF_WRES   1611808
#define OFF_ALPHA  1636384
#define OFF_WQ     1636400
#define OFF_WK     1833008
#define OFF_WV     2029616
#define OFF_WQP    2226224
#define OFF_WKP    2263088
#define OFF_WVP    2299952
#define OFF_WZQ    2373680
#define OFF_WZK    2374704
#define OFF_HEADW  2375728
#define OFF_WO     2375744
#define OFF_BO     2867264
#define OFF_LN1G   2867648
#define OFF_LN1B   2868032
#define OFF_WT1    2868416
#define OFF_BT1    3015872
#define OFF_WT2    3016256
#define OFF_BT2    3163712
#define OFF_WT3    3164096
#define OFF_BT3    3311552
#define OFF_LNTG   3311936
#define OFF_LNTB   3312320
#define OFF_WBB    3312704
#define OFF_BBB    3315008
#define IN_END     3315024

// ---- scratch (float offsets) ----
#define WS_FLAG    3315024
#define WS_WPOSTR  3315040
#define WS_WRESR   3316576
#define WS_HPOST   3322720
#define WS_ROWSUM  3339104
#define WS_ROTB    3355488
#define WS_WCATT   3392352      // bf16 Wcat^T [1920][384]
#define WS_WOT     3760992      // bf16 Wo^T [384][1280]
#define WS_WT1T    4006752
#define WS_WT2T    4080480
#define WS_WT3T    4154208
#define WS_PROJ    4227936      // 7,864,320 floats; overlays: Oext, x1s1/t1/t2/x3
#define WS_QB      12092256     // bf16 Q [32][1024][96]
#define WS_KB      13665120     // bf16 K [32][1024][96]
#define WS_VT      15237984     // bf16 V^T [32][160][1024]
// end 17,859,424 floats = 71.4 MB

#define OUT_ROT 6291456
#define OUT_TR  6328320

#define NSEG 32

struct P36 { const void* p[36]; };

__device__ __forceinline__ float b2f(bf16 x) { return __bfloat162float(x); }

__device__ __forceinline__ short f2bs(float x) {
  unsigned u = __float_as_uint(x);
  u += 0x7FFFu + ((u >> 16) & 1u);
  return (short)(u >> 16);
}

__device__ __forceinline__ int packbf(float lo, float hi) {
  return (int)(unsigned short)f2bs(lo) | ((int)f2bs(hi) << 16);
}

__device__ __forceinline__ float ldraw(const void* p, size_t i, int flag) {
  return flag ? b2f(((const bf16*)p)[i]) : ((const float*)p)[i];
}

__device__ __forceinline__ float wredf(float v) {
#pragma unroll
  for (int o = 1; o < 64; o <<= 1) v += __shfl_xor(v, o, 64);
  return v;
}

// ---------- dtype detect ----------
__global__ void detect_k(const unsigned int* __restrict__ mask_raw, int* __restrict__ flag) {
  if (threadIdx.x == 0 && blockIdx.x == 0) flag[0] = (mask_raw[0] == 0x3F803F80u) ? 1 : 0;
}

// ---------- convert inputs (minus z1/z2) into fp32 mirror ----------
__global__ __launch_bounds__(256) void cvtall_k(P36 ptrs, float* __restrict__ dst, const int* __restrict__ flagp) {
  const int i = blockIdx.x * 256 + threadIdx.x;
  if (i >= IN_END) return;
  const int flag = flagp[0];
  const int seg_src_t[NSEG] = {0,3,4,5,7,8,10,11,12,13,14,15,16,17,18,19,20,21,22,23,24,25,26,27,28,29,30,31,32,33,34,35};
  const int seg_dst_t[NSEG] = {OFF_S,OFF_QUAT,OFF_TRANS,OFF_MASK,OFF_BPOST,OFF_BRES,OFF_WPOST,OFF_WRES,OFF_ALPHA,
                               OFF_WQ,OFF_WK,OFF_WV,OFF_WQP,OFF_WKP,OFF_WVP,OFF_WZQ,OFF_WZK,OFF_HEADW,
                               OFF_WO,OFF_BO,OFF_LN1G,OFF_LN1B,OFF_WT1,OFF_BT1,OFF_WT2,OFF_BT2,OFF_WT3,OFF_BT3,
                               OFF_LNTG,OFF_LNTB,OFF_WBB,OFF_BBB};
  const int seg_cnt_t[NSEG] = {1572864,16384,12288,4096,4,16,6144,24576,1,
                               196608,196608,196608,36864,36864,73728,1024,1024,8,
                               491520,384,384,384,147456,384,147456,384,147456,384,
                               384,384,2304,6};
  int off = i, cnt = seg_cnt_t[0];
  const void* sp = ptrs.p[0];
#pragma unroll
  for (int k = 1; k < NSEG; k++) {
    if (i >= seg_dst_t[k]) { off = i - seg_dst_t[k]; cnt = seg_cnt_t[k]; sp = ptrs.p[seg_src_t[k]]; }
  }
  float v = 0.f;
  if (off < cnt) v = flag ? b2f(((const bf16*)sp)[off]) : ((const float*)sp)[off];
  dst[i] = v;
}

// ---------- fused weight transposes: fp32 [K][N] -> bf16 [N][K], LDS 32x32 tiles ----------
__global__ __launch_bounds__(256) void wprep_k(const float* __restrict__ ws, short* __restrict__ wsS) {
  const int jobs_src[10] = {OFF_WQ, OFF_WK, OFF_WV, OFF_WQP, OFF_WKP, OFF_WVP, OFF_WO, OFF_WT1, OFF_WT2, OFF_WT3};
  const int jobs_dst[10] = {WS_WCATT*2, WS_WCATT*2 + 512*384, WS_WCATT*2 + 1024*384, WS_WCATT*2 + 1536*384,
                            WS_WCATT*2 + 1632*384, WS_WCATT*2 + 1728*384, WS_WOT*2, WS_WT1T*2, WS_WT2T*2, WS_WT3T*2};
  const int jobs_K[10] = {384,384,384,384,384,384,1280,384,384,384};
  const int jobs_N[10] = {512,512,512,96,96,192,384,384,384,384};
  const int jobs_t0[10] = {0,192,384,576,612,648,720,1200,1344,1488};
  const int t = blockIdx.x;
  int j = 0;
#pragma unroll
  for (int k = 1; k < 10; k++) if (t >= jobs_t0[k]) j = k;
  const int tl = t - jobs_t0[j];
  const int K = jobs_K[j], N = jobs_N[j];
  const int ntn = N >> 5;
  const int kt = tl / ntn, nt = tl - kt * ntn;
  const int k0 = kt * 32, n0 = nt * 32;
  const float* src = ws + jobs_src[j];
  short* dst = wsS + jobs_dst[j];
  __shared__ float T[32][36];
  {
    const int r = threadIdx.x >> 3, cq = (threadIdx.x & 7) * 4;
    const float4 a = *(const float4*)(src + (size_t)(k0 + r) * N + n0 + cq);
    T[r][cq] = a.x; T[r][cq + 1] = a.y; T[r][cq + 2] = a.z; T[r][cq + 3] = a.w;
  }
  __syncthreads();
  {
    const int n = threadIdx.x >> 3, kq = (threadIdx.x & 7) * 4;
    short pk4[4];
#pragma unroll
    for (int e = 0; e < 4; e++) pk4[e] = f2bs(T[kq + e][n]);
    *(int2*)(dst + (size_t)(n0 + n) * K + k0 + kq) = *(const int2*)pk4;
  }
}

// ---------- reduce W_post / W_res over stream blocks ----------
__global__ __launch_bounds__(256) void wreduce_k(const float* __restrict__ Wpost, const float* __restrict__ Wres,
                                                 float* __restrict__ WpostR, float* __restrict__ WresR) {
  int i = blockIdx.x * 256 + threadIdx.x;
  if (i < CSD * 4) {
    int c = i >> 2, n = i & 3;
    float s = 0.f;
#pragma unroll
    for (int blk = 0; blk < 4; blk++) s += Wpost[(blk * CSD + c) * 4 + n];
    WpostR[i] = s;
  }
  if (i < CSD * 16) {
    int c = i >> 4, n = i & 15;
    float s = 0.f;
#pragma unroll
    for (int blk = 0; blk < 4; blk++) s += Wres[(blk * CSD + c) * 16 + n];
    WresR[i] = s;
  }
}

// ---------- per-residue: H_post, sinkhorn row-sums, quat->rot ----------
__global__ __launch_bounds__(64) void mhc_k(const float* __restrict__ sF, const float* __restrict__ quat,
                                            const float* __restrict__ bpost, const float* __restrict__ bres,
                                            const float* __restrict__ alpha_p, const float* __restrict__ WpostR,
                                            const float* __restrict__ WresR, float* __restrict__ hpost,
                                            float* __restrict__ rowsum, float* __restrict__ rotb) {
  const int bl = blockIdx.x, t = threadIdx.x;
  const float* sr = sF + (size_t)bl * CSD;
  float ssq = 0.f, dp[4] = {0.f, 0.f, 0.f, 0.f}, dr[16];
#pragma unroll
  for (int n = 0; n < 16; n++) dr[n] = 0.f;
#pragma unroll
  for (int e = 0; e < 6; e++) {
    const int c = t + e * 64;
    const float sv = sr[c];
    ssq = fmaf(sv, sv, ssq);
#pragma unroll
    for (int n = 0; n < 4; n++) dp[n] = fmaf(sv, WpostR[c * 4 + n], dp[n]);
#pragma unroll
    for (int n = 0; n < 16; n++) dr[n] = fmaf(sv, WresR[c * 16 + n], dr[n]);
  }
  ssq = wredf(ssq);
#pragma unroll
  for (int n = 0; n < 4; n++) dp[n] = wredf(dp[n]);
#pragma unroll
  for (int n = 0; n < 16; n++) dr[n] = wredf(dr[n]);
  const float alpha = alpha_p[0];
  const float invn = rsqrtf(ssq * (1.f / 384.f) + 1e-6f);
  if (t == 0) {
#pragma unroll
    for (int n = 0; n < 4; n++) {
      const float x = bpost[n] + alpha * invn * dp[n];
      hpost[bl * 4 + n] = 2.f / (1.f + __expf(-x));
    }
    float M[16];
    float mx = -1e30f;
#pragma unroll
    for (int k = 0; k < 16; k++) { M[k] = bres[k] + alpha * invn * dr[k]; mx = fmaxf(mx, M[k]); }
#pragma unroll
    for (int k = 0; k < 16; k++) M[k] = __expf(M[k] - mx);
    for (int it = 0; it < 20; it++) {
#pragma unroll
      for (int r = 0; r < 4; r++) {
        const float s4 = M[r * 4] + M[r * 4 + 1] + M[r * 4 + 2] + M[r * 4 + 3];
        const float iv = 1.f / (s4 + 1e-8f);
        M[r * 4] *= iv; M[r * 4 + 1] *= iv; M[r * 4 + 2] *= iv; M[r * 4 + 3] *= iv;
      }
#pragma unroll
      for (int c2 = 0; c2 < 4; c2++) {
        const float s4 = M[c2] + M[4 + c2] + M[8 + c2] + M[12 + c2];
        const float iv = 1.f / (s4 + 1e-8f);
        M[c2] *= iv; M[4 + c2] *= iv; M[8 + c2] *= iv; M[12 + c2] *= iv;
      }
    }
#pragma unroll
    for (int r = 0; r < 4; r++)
      rowsum[bl * 4 + r] = M[r * 4] + M[r * 4 + 1] + M[r * 4 + 2] + M[r * 4 + 3];
  }
  if (t == 1) {
    float w = quat[bl * 4 + 0], x = quat[bl * 4 + 1];
    float y = quat[bl * 4 + 2], z = quat[bl * 4 + 3];
    const float iq = rsqrtf(w * w + x * x + y * y + z * z + 1e-8f);
    w *= iq; x *= iq; y *= iq; z *= iq;
    float* R = rotb + (size_t)bl * 9;
    R[0] = 1.f - 2.f * (y * y + z * z); R[1] = 2.f * (x * y - w * z); R[2] = 2.f * (x * z + w * y);
    R[3] = 2.f * (x * y + w * z); R[4] = 1.f - 2.f * (x * x + z * z); R[5] = 2.f * (y * z - w * x);
    R[6] = 2.f * (x * z - w * y); R[7] = 2.f * (y * z + w * x); R[8] = 1.f - 2.f * (x * x + y * y);
  }
}

// ---------- MFMA bf16 GEMM: C[M,N](fp32) = A[M,K](fp32) @ Bt[N,K](bf16)^T (+bias)(+relu)
__global__ __launch_bounds__(256) void gemm_mfma_k(const float* __restrict__ A, const short* __restrict__ Bt,
                                                   const float* __restrict__ bias, float* __restrict__ C,
                                                   int M, int N, int K, int relu) {
  __shared__ __align__(16) short As[128 * 40];
  __shared__ __align__(16) short Bs[128 * 40];
  const int tid = threadIdx.x;
  const int wid = tid >> 6, lane = tid & 63;
  const int c15 = lane & 15, q = lane >> 4;
  const int bm = blockIdx.y, bn = blockIdx.x;
  const int m_wave = (wid & 1) * 64, n_wave = (wid >> 1) * 64;
  const float* Ab = A + (size_t)(bm * 128) * K;
  const short* Bb = Bt + (size_t)(bn * 128) * K;

  f4v acc[4][4];
#pragma unroll
  for (int mi = 0; mi < 4; mi++)
#pragma unroll
    for (int ni = 0; ni < 4; ni++) acc[mi][ni] = (f4v){0.f, 0.f, 0.f, 0.f};

  for (int k0 = 0; k0 < K; k0 += 32) {
    __syncthreads();
#pragma unroll
    for (int e = 0; e < 4; e++) {
      const int slot = tid + e * 256;
      const int m = slot >> 3, k4 = (slot & 7) * 4;
      const float4 a = *(const float4*)(Ab + (size_t)m * K + k0 + k4);
      short pk[4] = {f2bs(a.x), f2bs(a.y), f2bs(a.z), f2bs(a.w)};
      *(int2*)&As[m * 40 + k4] = *(const int2*)pk;
    }
#pragma unroll
    for (int e = 0; e < 2; e++) {
      const int slot = tid + e * 256;
      const int n = slot >> 2, k8 = (slot & 3) * 8;
      *(int4*)&Bs[n * 40 + k8] = *(const int4*)(Bb + (size_t)n * K + k0 + k8);
    }
    __syncthreads();
    s8v Af[4], Bf[4];
#pragma unroll
    for (int mi = 0; mi < 4; mi++) Af[mi] = *(const s8v*)&As[(m_wave + mi * 16 + c15) * 40 + q * 8];
#pragma unroll
    for (int ni = 0; ni < 4; ni++) Bf[ni] = *(const s8v*)&Bs[(n_wave + ni * 16 + c15) * 40 + q * 8];
#pragma unroll
    for (int mi = 0; mi < 4; mi++)
#pragma unroll
      for (int ni = 0; ni < 4; ni++)
        acc[mi][ni] = __builtin_amdgcn_mfma_f32_16x16x32_bf16(Af[mi], Bf[ni], acc[mi][ni], 0, 0, 0);
  }
#pragma unroll
  for (int mi = 0; mi < 4; mi++) {
#pragma unroll
    for (int r = 0; r < 4; r++) {
      const int row = bm * 128 + m_wave + mi * 16 + q * 4 + r;
      float* Cr = C + (size_t)row * N + bn * 128 + n_wave;
#pragma unroll
      for (int ni = 0; ni < 4; ni++) {
        const int col = bn * 128 + n_wave + ni * 16 + c15;
        float v = acc[mi][ni][r];
        if (bias != nullptr) v += bias[col];
        if (relu) v = fmaxf(v, 0.f);
        Cr[ni * 16 + c15] = v;
      }
    }
  }
}

// ---------- assemble (wave per residue): Q/K bf16 [bh][L][96], V^T bf16 [bh][160][L] ----------
__global__ __launch_bounds__(64) void assemble_k(const float* __restrict__ proj, const float* __restrict__ rotb,
                                                 const float* __restrict__ trans, const void* __restrict__ z1raw,
                                                 const void* __restrict__ z2raw, const float* __restrict__ Wzq,
                                                 const float* __restrict__ Wzk, const float* __restrict__ headw,
                                                 const int* __restrict__ flagp, short* __restrict__ Qb,
                                                 short* __restrict__ Kb, short* __restrict__ Vtb) {
  __shared__ float qt[8][16], kt[8][16];
  const int bl = blockIdx.x, lane = threadIdx.x;
  const int h = lane >> 3, sub = lane & 7;
  const int flag = flagp[0];
  const float* pr = proj + (size_t)bl * NPROJ;
  const float* R = rotb + (size_t)bl * 9;
  const float txx = trans[bl * 3 + 0], tyy = trans[bl * 3 + 1], tzz = trans[bl * 3 + 2];
  float gamma;
  { const float w = headw[h]; gamma = (w > 20.f) ? w : log1pf(__expf(w)); }
  const float wL = 0.57735026918962576f;  // sqrt(1/3)
  const float wC = 0.23570226039551584f;  // sqrt(2/(9*4))
  const float ch = wL * wC * 0.5f * gamma;
  const float qscale = wL * 0.125f;       // wL / sqrt(64)

  // z-dot split across the 8 lanes of each h-group
  float zq0 = 0.f, zq1 = 0.f, zk0 = 0.f, zk1 = 0.f;
  const size_t zbase = (size_t)bl * 256;
  for (int zz = sub; zz < 128; zz += 8) {
    const float a0 = ldraw(z1raw, zbase + zz, flag);
    const float a1 = ldraw(z1raw, zbase + 128 + zz, flag);
    const float wq = Wzq[zz * 8 + h], wk = Wzk[zz * 8 + h];
    zq0 = fmaf(a0, wq, zq0); zq1 = fmaf(a1, wq, zq1);
    zk0 = fmaf(a0, wk, zk0); zk1 = fmaf(a1, wk, zk1);
  }
#pragma unroll
  for (int o = 1; o < 8; o <<= 1) {
    zq0 += __shfl_xor(zq0, o, 64); zq1 += __shfl_xor(zq1, o, 64);
    zk0 += __shfl_xor(zk0, o, 64); zk1 += __shfl_xor(zk1, o, 64);
  }

  const int b = bl >> 10, l = bl & 1023;
  const int bh = b * NH + h;
  const size_t row = (size_t)bh * LL + l;
  short* Q = Qb + row * QDP;
  short* Kx = Kb + row * QDP;

  // main 64 cols: each lane packs 8
  {
    const float* ps = pr + h * 64 + sub * 8;
    const float4 a0 = ((const float4*)ps)[0], a1 = ((const float4*)ps)[1];
    int4 qi;
    qi.x = packbf(a0.x * qscale, a0.y * qscale); qi.y = packbf(a0.z * qscale, a0.w * qscale);
    qi.z = packbf(a1.x * qscale, a1.y * qscale); qi.w = packbf(a1.z * qscale, a1.w * qscale);
    ((int4*)Q)[sub] = qi;
    const float* pk = pr + 512 + h * 64 + sub * 8;
    const float4 b0 = ((const float4*)pk)[0], b1 = ((const float4*)pk)[1];
    int4 ki;
    ki.x = packbf(b0.x, b0.y); ki.y = packbf(b0.z, b0.w);
    ki.z = packbf(b1.x, b1.y); ki.w = packbf(b1.z, b1.w);
    ((int4*)Kx)[sub] = ki;
    const float* pv = pr + 1024 + h * 64 + sub * 8;
#pragma unroll
    for (int e = 0; e < 8; e++)
      Vtb[((size_t)bh * VDP + sub * 8 + e) * LL + l] = f2bs(pv[e]);
  }

  // points: lanes 0-3 -> q-points, 4-7 -> k-points
  {
    const float* pp = pr + ((sub < 4) ? 1536 : 1632) + h * 12 + (sub & 3) * 3;
    const float gx = R[0] * pp[0] + R[1] * pp[1] + R[2] * pp[2] + txx;
    const float gy = R[3] * pp[0] + R[4] * pp[1] + R[5] * pp[2] + tyy;
    const float gz = R[6] * pp[0] + R[7] * pp[1] + R[8] * pp[2] + tzz;
    float nrm = gx * gx + gy * gy + gz * gz;
    nrm += __shfl_xor(nrm, 1, 64);
    nrm += __shfl_xor(nrm, 2, 64);
    const float other = __shfl_xor(nrm, 4, 64);
    const float qn = (sub < 4) ? nrm : other;
    const float kn = (sub < 4) ? other : nrm;
    if (sub < 4) {
      qt[h][2 + sub * 3 + 0] = 2.f * ch * gx;
      qt[h][2 + sub * 3 + 1] = 2.f * ch * gy;
      qt[h][2 + sub * 3 + 2] = 2.f * ch * gz;
    } else {
      kt[h][2 + (sub - 4) * 3 + 0] = gx;
      kt[h][2 + (sub - 4) * 3 + 1] = gy;
      kt[h][2 + (sub - 4) * 3 + 2] = gz;
    }
    if (sub == 0) {
      qt[h][0] = wL * zq0; qt[h][1] = wL * zq1; qt[h][14] = -ch * qn; qt[h][15] = 1.f;
      kt[h][0] = zk0;      kt[h][1] = zk1;      kt[h][14] = 1.f;      kt[h][15] = -ch * kn;
    }
  }
  // single wave: LDS RAW handled by compiler waitcnt; pack tails
  {
    int4 z4; z4.x = 0; z4.y = 0; z4.z = 0; z4.w = 0;
    if (sub < 2) {
      const float* s4 = &qt[h][sub * 8];
      int4 qi;
      qi.x = packbf(s4[0], s4[1]); qi.y = packbf(s4[2], s4[3]);
      qi.z = packbf(s4[4], s4[5]); qi.w = packbf(s4[6], s4[7]);
      ((int4*)Q)[8 + sub] = qi;
    } else if (sub < 4) {
      const float* s4 = &kt[h][(sub - 2) * 8];
      int4 ki;
      ki.x = packbf(s4[0], s4[1]); ki.y = packbf(s4[2], s4[3]);
      ki.z = packbf(s4[4], s4[5]); ki.w = packbf(s4[6], s4[7]);
      ((int4*)Kx)[8 + sub - 2] = ki;
    } else if (sub == 4) ((int4*)Q)[10] = z4;
    else if (sub == 5) ((int4*)Q)[11] = z4;
    else if (sub == 6) ((int4*)Kx)[10] = z4;
    else ((int4*)Kx)[11] = z4;
  }
  // V points (lane sub -> v-point sub)
  {
    const float* pv3 = pr + 1728 + h * 24 + sub * 3;
    const float gx = R[0] * pv3[0] + R[1] * pv3[1] + R[2] * pv3[2] + txx;
    const float gy = R[3] * pv3[0] + R[4] * pv3[1] + R[5] * pv3[2] + tyy;
    const float gz = R[6] * pv3[0] + R[7] * pv3[1] + R[8] * pv3[2] + tzz;
    const int c = 64 + sub * 3;
    Vtb[((size_t)bh * VDP + c + 0) * LL + l] = f2bs(gx);
    Vtb[((size_t)bh * VDP + c + 1) * LL + l] = f2bs(gy);
    Vtb[((size_t)bh * VDP + c + 2) * LL + l] = f2bs(gz);
  }
  // V z2 cols 88..151
  {
    const size_t z2base = ((size_t)bl * NH + h) * 64 + sub * 8;
#pragma unroll
    for (int e = 0; e < 8; e++)
      Vtb[((size_t)bh * VDP + 88 + sub * 8 + e) * LL + l] = f2bs(ldraw(z2raw, z2base + e, flag));
    Vtb[((size_t)bh * VDP + 152 + sub) * LL + l] = 0;
  }
}

// ---------- MFMA flash attention v3: 8 waves, j-split halves, register prefetch pipeline ----------
__global__ __launch_bounds__(512, 4) void attn_k(const short* __restrict__ Qb, const short* __restrict__ Kb,
                                                 const short* __restrict__ Vtb, const float* __restrict__ maskF,
                                                 float* __restrict__ Oext) {
  __shared__ __align__(16) short smem[26624];   // 53,248 B
  short* Ks = smem;                    // [2][32][104]
  short* Vs = smem + 6656;             // [2][160][40]
  short* Ps = smem + 19456;            // [8][16][40]
  float* Msl = (float*)(smem + 24576); // [1024] full mask row
  const int tid = threadIdx.x;
  const int wid = tid >> 6, lane = tid & 63;
  const int c15 = lane & 15, q = lane >> 4;
  const int blk = blockIdx.x;
  const int bh = blk & 31, qt2 = blk >> 5;      // same-bh blocks share blk%8 -> same XCD
  const int b = bh >> 3, h = bh & 7;
  const int half = wid >> 2, mw = wid & 3;
  const int i0 = qt2 * 64 + mw * 16;

  const short* Kbase = Kb + (size_t)bh * LL * QDP;
  const short* Vbase = Vtb + (size_t)bh * VDP * LL;

  s8v Qa[3];
  const short* Qrow = Qb + ((size_t)bh * LL + i0 + c15) * QDP;
#pragma unroll
  for (int kc = 0; kc < 3; kc++) Qa[kc] = *(const s8v*)(Qrow + kc * 32 + q * 8);

  f4v Of[10];
#pragma unroll
  for (int vt = 0; vt < 10; vt++) Of[vt] = (f4v){0.f, 0.f, 0.f, 0.f};
  float mold[4] = {-1e30f, -1e30f, -1e30f, -1e30f};
  float lsum[4] = {0.f, 0.f, 0.f, 0.f};

  // mask preload (whole row)
  Msl[tid] = maskF[b * LL + tid];
  Msl[tid + 512] = maskF[b * LL + tid + 512];

  // staging index decomposition (fixed per thread)
  const int khs0 = tid / 384;
  const int kv0 = tid - khs0 * 384;
  const int krr0 = kv0 / 12, kcc0 = kv0 - krr0 * 12;
  int khs1 = 0, krr1 = 0, kcc1 = 0;
  if (tid < 256) { const int u = tid + 512; khs1 = u / 384; const int v2 = u - khs1 * 384; krr1 = v2 / 12; kcc1 = v2 - krr1 * 12; }
  const int vhs0 = tid / 640; const int vv0 = tid - vhs0 * 640; const int vcc0 = vv0 >> 2, vp0 = vv0 & 3;
  const int vhs1 = (tid + 512) / 640; const int vv1 = (tid + 512) - vhs1 * 640; const int vcc1 = vv1 >> 2, vp1 = vv1 & 3;
  int vhs2 = 0, vcc2 = 0, vp2 = 0;
  if (tid < 256) { const int u = tid + 1024; vhs2 = u / 640; const int v2 = u - vhs2 * 640; vcc2 = v2 >> 2; vp2 = v2 & 3; }

  // prefetch tile 0
  int4 kr0, kr1, vr0, vr1, vr2;
  kr0 = *(const int4*)(Kbase + (size_t)(khs0 * 512 + krr0) * QDP + kcc0 * 8);
  if (tid < 256) kr1 = *(const int4*)(Kbase + (size_t)(khs1 * 512 + krr1) * QDP + kcc1 * 8);
  vr0 = *(const int4*)(Vbase + (size_t)vcc0 * LL + vhs0 * 512 + vp0 * 8);
  vr1 = *(const int4*)(Vbase + (size_t)vcc1 * LL + vhs1 * 512 + vp1 * 8);
  if (tid < 256) vr2 = *(const int4*)(Vbase + (size_t)vcc2 * LL + vhs2 * 512 + vp2 * 8);

  short* Ksl = Ks + half * 3328;
  short* Vsl = Vs + half * 6400;
  short* Pl = Ps + wid * 640;

  for (int jt = 0; jt < 16; jt++) {
    const int j0 = jt * 32;
    __syncthreads();   // prior compute done (jt=0: also orders Msl writes)
    *(int4*)&Ks[khs0 * 3328 + krr0 * 104 + kcc0 * 8] = kr0;
    if (tid < 256) *(int4*)&Ks[khs1 * 3328 + krr1 * 104 + kcc1 * 8] = kr1;
    *(int4*)&Vs[vhs0 * 6400 + vcc0 * 40 + vp0 * 8] = vr0;
    *(int4*)&Vs[vhs1 * 6400 + vcc1 * 40 + vp1 * 8] = vr1;
    if (tid < 256) *(int4*)&Vs[vhs2 * 6400 + vcc2 * 40 + vp2 * 8] = vr2;
    __syncthreads();
    if (jt < 15) {     // prefetch next tile into registers (overlaps compute)
      const int j0n = j0 + 32;
      kr0 = *(const int4*)(Kbase + (size_t)(khs0 * 512 + j0n + krr0) * QDP + kcc0 * 8);
      if (tid < 256) kr1 = *(const int4*)(Kbase + (size_t)(khs1 * 512 + j0n + krr1) * QDP + kcc1 * 8);
      vr0 = *(const int4*)(Vbase + (size_t)vcc0 * LL + vhs0 * 512 + j0n + vp0 * 8);
      vr1 = *(const int4*)(Vbase + (size_t)vcc1 * LL + vhs1 * 512 + j0n + vp1 * 8);
      if (tid < 256) vr2 = *(const int4*)(Vbase + (size_t)vcc2 * LL + vhs2 * 512 + j0n + vp2 * 8);
    }

    f4v Sf0 = (f4v){0.f, 0.f, 0.f, 0.f}, Sf1 = (f4v){0.f, 0.f, 0.f, 0.f};
#pragma unroll
    for (int kc = 0; kc < 3; kc++) {
      const s8v K0 = *(const s8v*)&Ksl[c15 * 104 + kc * 32 + q * 8];
      const s8v K1 = *(const s8v*)&Ksl[(16 + c15) * 104 + kc * 32 + q * 8];
      Sf0 = __builtin_amdgcn_mfma_f32_16x16x32_bf16(Qa[kc], K0, Sf0, 0, 0, 0);
      Sf1 = __builtin_amdgcn_mfma_f32_16x16x32_bf16(Qa[kc], K1, Sf1, 0, 0, 0);
    }
    const float mv0 = Msl[half * 512 + j0 + c15];
    const float mv1 = Msl[half * 512 + j0 + 16 + c15];
    float lg0[4], lg1[4], tm[4], p0[4], p1[4];
#pragma unroll
    for (int r = 0; r < 4; r++) {
      lg0[r] = (mv0 > 0.f) ? Sf0[r] : -1e9f;
      lg1[r] = (mv1 > 0.f) ? Sf1[r] : -1e9f;
      tm[r] = fmaxf(lg0[r], lg1[r]);
    }
#pragma unroll
    for (int r = 0; r < 4; r++) {
      tm[r] = fmaxf(tm[r], __shfl_xor(tm[r], 1, 64));
      tm[r] = fmaxf(tm[r], __shfl_xor(tm[r], 2, 64));
      tm[r] = fmaxf(tm[r], __shfl_xor(tm[r], 4, 64));
      tm[r] = fmaxf(tm[r], __shfl_xor(tm[r], 8, 64));
    }
    const bool need = (tm[0] > mold[0]) | (tm[1] > mold[1]) | (tm[2] > mold[2]) | (tm[3] > mold[3]);
    if (__any(need)) {
      float al[4];
#pragma unroll
      for (int r = 0; r < 4; r++) {
        const float mn = fmaxf(mold[r], tm[r]);
        al[r] = __expf(mold[r] - mn);
        mold[r] = mn;
        p0[r] = __expf(lg0[r] - mn);
        p1[r] = __expf(lg1[r] - mn);
        lsum[r] = lsum[r] * al[r] + p0[r] + p1[r];
      }
#pragma unroll
      for (int vt = 0; vt < 10; vt++) {
#pragma unroll
        for (int r = 0; r < 4; r++) Of[vt][r] *= al[r];
      }
    } else {
#pragma unroll
      for (int r = 0; r < 4; r++) {
        p0[r] = __expf(lg0[r] - mold[r]);
        p1[r] = __expf(lg1[r] - mold[r]);
        lsum[r] += p0[r] + p1[r];
      }
    }
#pragma unroll
    for (int r = 0; r < 4; r++) {
      Pl[(q * 4 + r) * 40 + c15] = f2bs(p0[r]);
      Pl[(q * 4 + r) * 40 + 16 + c15] = f2bs(p1[r]);
    }
    const s8v Pa = *(const s8v*)&Pl[c15 * 40 + q * 8];
#pragma unroll
    for (int vt = 0; vt < 10; vt++) {
      const s8v Vf = *(const s8v*)&Vsl[(vt * 16 + c15) * 40 + q * 8];
      Of[vt] = __builtin_amdgcn_mfma_f32_16x16x32_bf16(Pa, Vf, Of[vt], 0, 0, 0);
    }
  }
#pragma unroll
  for (int r = 0; r < 4; r++) {
    lsum[r] += __shfl_xor(lsum[r], 1, 64);
    lsum[r] += __shfl_xor(lsum[r], 2, 64);
    lsum[r] += __shfl_xor(lsum[r], 4, 64);
    lsum[r] += __shfl_xor(lsum[r], 8, 64);
  }
  // merge halves through LDS
  float* Obuf = (float*)smem;              // [4][16][160] = 40,960 B
  float* Mbuf = (float*)(smem + 20480);    // [64]
  float* Lbuf = Mbuf + 64;                 // [64]
  __syncthreads();
  if (half == 1) {
#pragma unroll
    for (int r = 0; r < 4; r++) {
      const int rowi = mw * 16 + q * 4 + r;
#pragma unroll
      for (int vt = 0; vt < 10; vt++) Obuf[rowi * 160 + vt * 16 + c15] = Of[vt][r];
      if (c15 == 0) { Mbuf[rowi] = mold[r]; Lbuf[rowi] = lsum[r]; }
    }
  }
  __syncthreads();
  if (half == 0) {
#pragma unroll
    for (int r = 0; r < 4; r++) {
      const int rowi = mw * 16 + q * 4 + r;
      const float m2 = Mbuf[rowi], l2 = Lbuf[rowi];
      const float mx = fmaxf(mold[r], m2);
      const float a1 = __expf(mold[r] - mx), a2 = __expf(m2 - mx);
      const float inv = 1.f / (lsum[r] * a1 + l2 * a2);
      const int i = i0 + q * 4 + r;
      float* Or = Oext + ((size_t)(b * LL + i) * NH + h) * VDP;
#pragma unroll
      for (int vt = 0; vt < 10; vt++)
        Or[vt * 16 + c15] = (Of[vt][r] * a1 + Obuf[rowi * 160 + vt * 16 + c15] * a2) * inv;
    }
  }
}

// ---------- feat assembly (wave per residue) ----------
__global__ __launch_bounds__(64) void feat_k(const float* __restrict__ Oext, const float* __restrict__ rotb,
                                             const float* __restrict__ trans, float* __restrict__ feat) {
  const int bl = blockIdx.x, lane = threadIdx.x;
  const int h = lane >> 3, sub = lane & 7;
  const float* O = Oext + ((size_t)bl * 8 + h) * VDP;
  float* f = feat + (size_t)bl * FEATD;
  {
    const float4 a0 = ((const float4*)(O + sub * 8))[0], a1 = ((const float4*)(O + sub * 8))[1];
    ((float4*)(f + h * 64 + sub * 8))[0] = a0;
    ((float4*)(f + h * 64 + sub * 8))[1] = a1;
    const float4 z0 = ((const float4*)(O + 88 + sub * 8))[0], z1 = ((const float4*)(O + 88 + sub * 8))[1];
    ((float4*)(f + 768 + h * 64 + sub * 8))[0] = z0;
    ((float4*)(f + 768 + h * 64 + sub * 8))[1] = z1;
  }
  const float* R = rotb + (size_t)bl * 9;
  const float txx = trans[bl * 3 + 0], tyy = trans[bl * 3 + 1], tzz = trans[bl * 3 + 2];
  {
    const float dx = O[64 + sub * 3 + 0] - txx;
    const float dy = O[64 + sub * 3 + 1] - tyy;
    const float dz = O[64 + sub * 3 + 2] - tzz;
    const float lx = R[0] * dx + R[3] * dy + R[6] * dz;   // R^T * diff
    const float ly = R[1] * dx + R[4] * dy + R[7] * dz;
    const float lz = R[2] * dx + R[5] * dy + R[8] * dz;
    f[512 + h * 24 + sub * 3 + 0] = lx;
    f[512 + h * 24 + sub * 3 + 1] = ly;
    f[512 + h * 24 + sub * 3 + 2] = lz;
    f[704 + h * 8 + sub] = sqrtf(lx * lx + ly * ly + lz * lz + 1e-8f);
  }
}

// ---------- LayerNorm(x + resid) (one wave per row) ----------
__global__ __launch_bounds__(64) void ln_k(const float* __restrict__ x, const float* __restrict__ resid,
                                           const float* __restrict__ g, const float* __restrict__ bta,
                                           float* __restrict__ out) {
  const int row = blockIdx.x, t = threadIdx.x;
  const float* xr = x + (size_t)row * CSD;
  const float* rr = resid + (size_t)row * CSD;
  float v[6];
  float s = 0.f;
#pragma unroll
  for (int e = 0; e < 6; e++) {
    const int c = t + e * 64;
    v[e] = xr[c] + rr[c];
    s += v[e];
  }
  s = wredf(s);
  const float mu = s * (1.f / 384.f);
  float var = 0.f;
#pragma unroll
  for (int e = 0; e < 6; e++) { const float d = v[e] - mu; var = fmaf(d, d, var); }
  var = wredf(var) * (1.f / 384.f);
  const float inv = rsqrtf(var + 1e-5f);
#pragma unroll
  for (int e = 0; e < 6; e++) {
    const int c = t + e * 64;
    out[(size_t)row * CSD + c] = (v[e] - mu) * inv * g[c] + bta[c];
  }
}

// ---------- fused tail LN + backbone update + mHC combine ----------
__global__ __launch_bounds__(64) void lnfinal_k(const float* __restrict__ x /*x3*/, const float* __restrict__ resid /*s1*/,
                                                const float* __restrict__ g, const float* __restrict__ bta,
                                                const float* __restrict__ sF, const float* __restrict__ rotb,
                                                const float* __restrict__ trans, const float* __restrict__ hpost,
                                                const float* __restrict__ rowsum, const float* __restrict__ Wbb,
                                                const float* __restrict__ bbb, const int* __restrict__ flagp,
                                                void* __restrict__ outv) {
  const int bl = blockIdx.x, t = threadIdx.x;
  const int flag = flagp[0];
  bf16* outb = (bf16*)outv;
  float* outf = (float*)outv;
  // --- LN(x + resid) -> si values in registers ---
  const float* xr = x + (size_t)bl * CSD;
  const float* rr = resid + (size_t)bl * CSD;
  float v[6];
  float s = 0.f;
#pragma unroll
  for (int e = 0; e < 6; e++) {
    const int c = t + e * 64;
    v[e] = xr[c] + rr[c];
    s += v[e];
  }
  s = wredf(s);
  const float mu = s * (1.f / 384.f);
  float var = 0.f;
#pragma unroll
  for (int e = 0; e < 6; e++) { const float d = v[e] - mu; var = fmaf(d, d, var); }
  var = wredf(var) * (1.f / 384.f);
  const float inv = rsqrtf(var + 1e-5f);
  float si6[6];
#pragma unroll
  for (int e = 0; e < 6; e++) {
    const int c = t + e * 64;
    si6[e] = (v[e] - mu) * inv * g[c] + bta[c];
  }
  // --- backbone update ---
  float d6[6] = {0.f, 0.f, 0.f, 0.f, 0.f, 0.f};
#pragma unroll
  for (int e = 0; e < 6; e++) {
    const int c = t + e * 64;
#pragma unroll
    for (int u = 0; u < 6; u++) d6[u] = fmaf(si6[e], Wbb[c * 6 + u], d6[u]);
  }
#pragma unroll
  for (int u = 0; u < 6; u++) d6[u] = wredf(d6[u]);
  float upd[6];
#pragma unroll
  for (int u = 0; u < 6; u++) upd[u] = d6[u] + bbb[u];
  const float* R = rotb + (size_t)bl * 9;
  if (t == 0) {
    float w = 1.f, x2 = upd[0], y = upd[1], z = upd[2];
    const float iq = rsqrtf(w * w + x2 * x2 + y * y + z * z + 1e-8f);
    w *= iq; x2 *= iq; y *= iq; z *= iq;
    const float Ru[9] = {1.f - 2.f * (y * y + z * z), 2.f * (x2 * y - w * z), 2.f * (x2 * z + w * y),
                         2.f * (x2 * y + w * z), 1.f - 2.f * (x2 * x2 + z * z), 2.f * (y * z - w * x2),
                         2.f * (x2 * z - w * y), 2.f * (y * z + w * x2), 1.f - 2.f * (x2 * x2 + y * y)};
#pragma unroll
    for (int i = 0; i < 3; i++)
#pragma unroll
      for (int j = 0; j < 3; j++) {
        const float rv = R[i * 3 + 0] * Ru[0 + j] + R[i * 3 + 1] * Ru[3 + j] + R[i * 3 + 2] * Ru[6 + j];
        const size_t o = OUT_ROT + (size_t)bl * 9 + i * 3 + j;
        if (flag) outb[o] = __float2bfloat16(rv); else outf[o] = rv;
      }
#pragma unroll
    for (int i = 0; i < 3; i++) {
      const float tv = R[i * 3 + 0] * upd[3] + R[i * 3 + 1] * upd[4] + R[i * 3 + 2] * upd[5] + trans[bl * 3 + i];
      const size_t o = OUT_TR + (size_t)bl * 3 + i;
      if (flag) outb[o] = __float2bfloat16(tv); else outf[o] = tv;
    }
  }
  // --- mHC combine ---
  const float hp0 = hpost[bl * 4 + 0], hp1 = hpost[bl * 4 + 1], hp2 = hpost[bl * 4 + 2], hp3 = hpost[bl * 4 + 3];
  const float rs0 = rowsum[bl * 4 + 0], rs1 = rowsum[bl * 4 + 1], rs2 = rowsum[bl * 4 + 2], rs3 = rowsum[bl * 4 + 3];
  const float* sr = sF + (size_t)bl * CSD;
#pragma unroll
  for (int e = 0; e < 6; e++) {
    const int c = t + e * 64;
    const float sv = sr[c], sp = si6[e];
    const size_t base = (size_t)bl * 4 * CSD + c;
    const float o0 = rs0 * sv + hp0 * sp;
    const float o1 = rs1 * sv + hp1 * sp;
    const float o2 = rs2 * sv + hp2 * sp;
    const float o3 = rs3 * sv + hp3 * sp;
    if (flag) {
      outb[base + 0 * CSD] = __float2bfloat16(o0);
      outb[base + 1 * CSD] = __float2bfloat16(o1);
      outb[base + 2 * CSD] = __float2bfloat16(o2);
      outb[base + 3 * CSD] = __float2bfloat16(o3);
    } else {
      outf[base + 0 * CSD] = o0;
      outf[base + 1 * CSD] = o1;
      outf[base + 2 * CSD] = o2;
      outf[base + 3 * CSD] = o3;
    }
  }
}

extern "C" void kernel_launch(void* const* d_in, const int* in_sizes, int n_in,
                              void* d_out, int out_size, void* d_ws, size_t ws_size,
                              hipStream_t stream) {
  float* ws = (float*)d_ws;
  int* flag = (int*)(ws + WS_FLAG);

  P36 ptrs;
  for (int i = 0; i < 36; i++) ptrs.p[i] = d_in[i];

  float* sF     = ws + OFF_S;
  float* WpostR = ws + WS_WPOSTR;
  float* WresR  = ws + WS_WRESR;
  float* hpost  = ws + WS_HPOST;
  float* rowsum = ws + WS_ROWSUM;
  float* rotb   = ws + WS_ROTB;
  short* WcatT  = (short*)(ws + WS_WCATT);
  short* WoT    = (short*)(ws + WS_WOT);
  short* Wt1T   = (short*)(ws + WS_WT1T);
  short* Wt2T   = (short*)(ws + WS_WT2T);
  short* Wt3T   = (short*)(ws + WS_WT3T);
  float* proj   = ws + WS_PROJ;
  short* Qb     = (short*)(ws + WS_QB);
  short* Kb     = (short*)(ws + WS_KB);
  short* Vtb    = (short*)(ws + WS_VT);
  float* Oext   = ws + WS_PROJ;               // overlay (proj dead after assemble)
  float* featb  = ws + WS_QB;                 // overlay, spans QB..VT (dead after attn)
  float* x1s1   = ws + WS_PROJ;               // overlay (Oext dead after feat_k)
  float* t1b    = ws + WS_PROJ + 1572864;
  float* t2b    = ws + WS_PROJ + 3145728;
  float* x3     = ws + WS_PROJ + 4718592;

  detect_k<<<1, 64, 0, stream>>>((const unsigned int*)d_in[5], flag);
  cvtall_k<<<(IN_END + 255) / 256, 256, 0, stream>>>(ptrs, ws, flag);
  wprep_k<<<1632, 256, 0, stream>>>(ws, (short*)ws);
  wreduce_k<<<24, 256, 0, stream>>>(ws + OFF_WPOST, ws + OFF_WRES, WpostR, WresR);
  mhc_k<<<BL, 64, 0, stream>>>(sF, ws + OFF_QUAT, ws + OFF_BPOST, ws + OFF_BRES, ws + OFF_ALPHA,
                               WpostR, WresR, hpost, rowsum, rotb);
  gemm_mfma_k<<<dim3(15, 32), 256, 0, stream>>>(sF, WcatT, nullptr, proj, BL, NPROJ, CSD, 0);
  assemble_k<<<BL, 64, 0, stream>>>(proj, rotb, ws + OFF_TRANS, d_in[1], d_in[2],
                                    ws + OFF_WZQ, ws + OFF_WZK, ws + OFF_HEADW, flag, Qb, Kb, Vtb);
  attn_k<<<512, 512, 0, stream>>>(Qb, Kb, Vtb, ws + OFF_MASK, Oext);
  feat_k<<<BL, 64, 0, stream>>>(Oext, rotb, ws + OFF_TRANS, featb);
  gemm_mfma_k<<<dim3(3, 32), 256, 0, stream>>>(featb, WoT, ws + OFF_BO, x1s1, BL, CSD, FEATD, 0);
  ln_k<<<BL, 64, 0, stream>>>(x1s1, sF, ws + OFF_LN1G, ws + OFF_LN1B, x1s1);                   // s1
  gemm_mfma_k<<<dim3(3, 32), 256, 0, stream>>>(x1s1, Wt1T, ws + OFF_BT1, t1b, BL, CSD, CSD, 1);
  gemm_mfma_k<<<dim3(3, 32), 256, 0, stream>>>(t1b, Wt2T, ws + OFF_BT2, t2b, BL, CSD, CSD, 1);
  gemm_mfma_k<<<dim3(3, 32), 256, 0, stream>>>(t2b, Wt3T, ws + OFF_BT3, x3, BL, CSD, CSD, 0);
  lnfinal_k<<<BL, 64, 0, stream>>>(x3, x1s1, ws + OFF_LNTG, ws + OFF_LNTB, sF, rotb,
                                   ws + OFF_TRANS, hpost, rowsum, ws + OFF_WBB, ws + OFF_BBB,
                                   flag, d_out);
}

// Round 8
// 482.278 us; speedup vs baseline: 1.2119x; 1.2119x over previous
//
#include <hip/hip_runtime.h>
#include <hip/hip_bf16.h>

typedef __hip_bfloat16 bf16;
typedef float f4v __attribute__((ext_vector_type(4)));
typedef short s8v __attribute__((ext_vector_type(8)));

#define CSD    384
#define LL     1024
#define NH     8
#define BL     4096        // B*L
#define NPROJ  1920
#define QDP    96          // 80 real ext-Q/K dims, padded to 96
#define VDP    160         // 152 real ext-V dims, padded to 160
#define FEATD  1280

// ---- fp32 input mirror (z1/z2 NOT mirrored — read raw in assemble) ----
#define OFF_S      0
#define OFF_QUAT   1572864
#define OFF_TRANS  1589248
#define OFF_MASK   1601536
#define OFF_BPOST  1605632
#define OFF_BRES   1605648
#define OFF_WPOST  1605664
#define OFF_WRES   1611808
#define OFF_ALPHA  1636384
#define OFF_WQ     1636400
#define OFF_WK     1833008
#define OFF_WV     2029616
#define OFF_WQP    2226224
#define OFF_WKP    2263088
#define OFF_WVP    2299952
#define OFF_WZQ    2373680
#define OFF_WZK    2374704
#define OFF_HEADW  2375728
#define OFF_WO     2375744
#define OFF_BO     2867264
#define OFF_LN1G   2867648
#define OFF_LN1B   2868032
#define OFF_WT1    2868416
#define OFF_BT1    3015872
#define OFF_WT2    3016256
#define OFF_BT2    3163712
#define OFF_WT3    3164096
#define OFF_BT3    3311552
#define OFF_LNTG   3311936
#define OFF_LNTB   3312320
#define OFF_WBB    3312704
#define OFF_BBB    3315008
#define IN_END     3315024

// ---- scratch (float offsets) ----
#define WS_FLAG    3315024
#define WS_WPOSTR  3315040
#define WS_WRESR   3316576
#define WS_HPOST   3322720
#define WS_ROWSUM  3339104
#define WS_ROTB    3355488
#define WS_WCATT   3392352      // bf16 Wcat^T [1920][384]
#define WS_WOT     3760992      // bf16 Wo^T [384][1280]
#define WS_WT1T    4006752
#define WS_WT2T    4080480
#define WS_WT3T    4154208
#define WS_PROJ    4227936      // 7,864,320 floats; overlays: Oext, x1s1/t1/t2/x3
#define WS_QB      12092256     // bf16 Q [32][1024][96]
#define WS_KB      13665120     // bf16 K [32][1024][96]
#define WS_VT      15237984     // bf16 V^T [32][160][1024]
// end 17,859,424 floats = 71.4 MB

#define OUT_ROT 6291456
#define OUT_TR  6328320

#define NSEG 32

struct P36 { const void* p[36]; };

__device__ __forceinline__ float b2f(bf16 x) { return __bfloat162float(x); }

__device__ __forceinline__ short f2bs(float x) {
  unsigned u = __float_as_uint(x);
  u += 0x7FFFu + ((u >> 16) & 1u);
  return (short)(u >> 16);
}

__device__ __forceinline__ int packbf(float lo, float hi) {
  return (int)(unsigned short)f2bs(lo) | ((int)f2bs(hi) << 16);
}

__device__ __forceinline__ float ldraw(const void* p, size_t i, int flag) {
  return flag ? b2f(((const bf16*)p)[i]) : ((const float*)p)[i];
}

__device__ __forceinline__ float wredf(float v) {
#pragma unroll
  for (int o = 1; o < 64; o <<= 1) v += __shfl_xor(v, o, 64);
  return v;
}

// ---------- dtype detect ----------
__global__ void detect_k(const unsigned int* __restrict__ mask_raw, int* __restrict__ flag) {
  if (threadIdx.x == 0 && blockIdx.x == 0) flag[0] = (mask_raw[0] == 0x3F803F80u) ? 1 : 0;
}

// ---------- convert inputs (minus z1/z2) into fp32 mirror ----------
__global__ __launch_bounds__(256) void cvtall_k(P36 ptrs, float* __restrict__ dst, const int* __restrict__ flagp) {
  const int i = blockIdx.x * 256 + threadIdx.x;
  if (i >= IN_END) return;
  const int flag = flagp[0];
  const int seg_src_t[NSEG] = {0,3,4,5,7,8,10,11,12,13,14,15,16,17,18,19,20,21,22,23,24,25,26,27,28,29,30,31,32,33,34,35};
  const int seg_dst_t[NSEG] = {OFF_S,OFF_QUAT,OFF_TRANS,OFF_MASK,OFF_BPOST,OFF_BRES,OFF_WPOST,OFF_WRES,OFF_ALPHA,
                               OFF_WQ,OFF_WK,OFF_WV,OFF_WQP,OFF_WKP,OFF_WVP,OFF_WZQ,OFF_WZK,OFF_HEADW,
                               OFF_WO,OFF_BO,OFF_LN1G,OFF_LN1B,OFF_WT1,OFF_BT1,OFF_WT2,OFF_BT2,OFF_WT3,OFF_BT3,
                               OFF_LNTG,OFF_LNTB,OFF_WBB,OFF_BBB};
  const int seg_cnt_t[NSEG] = {1572864,16384,12288,4096,4,16,6144,24576,1,
                               196608,196608,196608,36864,36864,73728,1024,1024,8,
                               491520,384,384,384,147456,384,147456,384,147456,384,
                               384,384,2304,6};
  int off = i, cnt = seg_cnt_t[0];
  const void* sp = ptrs.p[0];
#pragma unroll
  for (int k = 1; k < NSEG; k++) {
    if (i >= seg_dst_t[k]) { off = i - seg_dst_t[k]; cnt = seg_cnt_t[k]; sp = ptrs.p[seg_src_t[k]]; }
  }
  float v = 0.f;
  if (off < cnt) v = flag ? b2f(((const bf16*)sp)[off]) : ((const float*)sp)[off];
  dst[i] = v;
}

// ---------- fused weight transposes: fp32 [K][N] -> bf16 [N][K], LDS 32x32 tiles ----------
__global__ __launch_bounds__(256) void wprep_k(const float* __restrict__ ws, short* __restrict__ wsS) {
  const int jobs_src[10] = {OFF_WQ, OFF_WK, OFF_WV, OFF_WQP, OFF_WKP, OFF_WVP, OFF_WO, OFF_WT1, OFF_WT2, OFF_WT3};
  const int jobs_dst[10] = {WS_WCATT*2, WS_WCATT*2 + 512*384, WS_WCATT*2 + 1024*384, WS_WCATT*2 + 1536*384,
                            WS_WCATT*2 + 1632*384, WS_WCATT*2 + 1728*384, WS_WOT*2, WS_WT1T*2, WS_WT2T*2, WS_WT3T*2};
  const int jobs_K[10] = {384,384,384,384,384,384,1280,384,384,384};
  const int jobs_N[10] = {512,512,512,96,96,192,384,384,384,384};
  const int jobs_t0[10] = {0,192,384,576,612,648,720,1200,1344,1488};
  const int t = blockIdx.x;
  int j = 0;
#pragma unroll
  for (int k = 1; k < 10; k++) if (t >= jobs_t0[k]) j = k;
  const int tl = t - jobs_t0[j];
  const int K = jobs_K[j], N = jobs_N[j];
  const int ntn = N >> 5;
  const int kt = tl / ntn, nt = tl - kt * ntn;
  const int k0 = kt * 32, n0 = nt * 32;
  const float* src = ws + jobs_src[j];
  short* dst = wsS + jobs_dst[j];
  __shared__ float T[32][36];
  {
    const int r = threadIdx.x >> 3, cq = (threadIdx.x & 7) * 4;
    const float4 a = *(const float4*)(src + (size_t)(k0 + r) * N + n0 + cq);
    T[r][cq] = a.x; T[r][cq + 1] = a.y; T[r][cq + 2] = a.z; T[r][cq + 3] = a.w;
  }
  __syncthreads();
  {
    const int n = threadIdx.x >> 3, kq = (threadIdx.x & 7) * 4;
    short pk4[4];
#pragma unroll
    for (int e = 0; e < 4; e++) pk4[e] = f2bs(T[kq + e][n]);
    *(int2*)(dst + (size_t)(n0 + n) * K + k0 + kq) = *(const int2*)pk4;
  }
}

// ---------- reduce W_post / W_res over stream blocks ----------
__global__ __launch_bounds__(256) void wreduce_k(const float* __restrict__ Wpost, const float* __restrict__ Wres,
                                                 float* __restrict__ WpostR, float* __restrict__ WresR) {
  int i = blockIdx.x * 256 + threadIdx.x;
  if (i < CSD * 4) {
    int c = i >> 2, n = i & 3;
    float s = 0.f;
#pragma unroll
    for (int blk = 0; blk < 4; blk++) s += Wpost[(blk * CSD + c) * 4 + n];
    WpostR[i] = s;
  }
  if (i < CSD * 16) {
    int c = i >> 4, n = i & 15;
    float s = 0.f;
#pragma unroll
    for (int blk = 0; blk < 4; blk++) s += Wres[(blk * CSD + c) * 16 + n];
    WresR[i] = s;
  }
}

// ---------- per-residue: H_post, sinkhorn row-sums, quat->rot ----------
__global__ __launch_bounds__(64) void mhc_k(const float* __restrict__ sF, const float* __restrict__ quat,
                                            const float* __restrict__ bpost, const float* __restrict__ bres,
                                            const float* __restrict__ alpha_p, const float* __restrict__ WpostR,
                                            const float* __restrict__ WresR, float* __restrict__ hpost,
                                            float* __restrict__ rowsum, float* __restrict__ rotb) {
  const int bl = blockIdx.x, t = threadIdx.x;
  const float* sr = sF + (size_t)bl * CSD;
  float ssq = 0.f, dp[4] = {0.f, 0.f, 0.f, 0.f}, dr[16];
#pragma unroll
  for (int n = 0; n < 16; n++) dr[n] = 0.f;
#pragma unroll
  for (int e = 0; e < 6; e++) {
    const int c = t + e * 64;
    const float sv = sr[c];
    ssq = fmaf(sv, sv, ssq);
#pragma unroll
    for (int n = 0; n < 4; n++) dp[n] = fmaf(sv, WpostR[c * 4 + n], dp[n]);
#pragma unroll
    for (int n = 0; n < 16; n++) dr[n] = fmaf(sv, WresR[c * 16 + n], dr[n]);
  }
  ssq = wredf(ssq);
#pragma unroll
  for (int n = 0; n < 4; n++) dp[n] = wredf(dp[n]);
#pragma unroll
  for (int n = 0; n < 16; n++) dr[n] = wredf(dr[n]);
  const float alpha = alpha_p[0];
  const float invn = rsqrtf(ssq * (1.f / 384.f) + 1e-6f);
  if (t == 0) {
#pragma unroll
    for (int n = 0; n < 4; n++) {
      const float x = bpost[n] + alpha * invn * dp[n];
      hpost[bl * 4 + n] = 2.f / (1.f + __expf(-x));
    }
    float M[16];
    float mx = -1e30f;
#pragma unroll
    for (int k = 0; k < 16; k++) { M[k] = bres[k] + alpha * invn * dr[k]; mx = fmaxf(mx, M[k]); }
#pragma unroll
    for (int k = 0; k < 16; k++) M[k] = __expf(M[k] - mx);
    for (int it = 0; it < 20; it++) {
#pragma unroll
      for (int r = 0; r < 4; r++) {
        const float s4 = M[r * 4] + M[r * 4 + 1] + M[r * 4 + 2] + M[r * 4 + 3];
        const float iv = 1.f / (s4 + 1e-8f);
        M[r * 4] *= iv; M[r * 4 + 1] *= iv; M[r * 4 + 2] *= iv; M[r * 4 + 3] *= iv;
      }
#pragma unroll
      for (int c2 = 0; c2 < 4; c2++) {
        const float s4 = M[c2] + M[4 + c2] + M[8 + c2] + M[12 + c2];
        const float iv = 1.f / (s4 + 1e-8f);
        M[c2] *= iv; M[4 + c2] *= iv; M[8 + c2] *= iv; M[12 + c2] *= iv;
      }
    }
#pragma unroll
    for (int r = 0; r < 4; r++)
      rowsum[bl * 4 + r] = M[r * 4] + M[r * 4 + 1] + M[r * 4 + 2] + M[r * 4 + 3];
  }
  if (t == 1) {
    float w = quat[bl * 4 + 0], x = quat[bl * 4 + 1];
    float y = quat[bl * 4 + 2], z = quat[bl * 4 + 3];
    const float iq = rsqrtf(w * w + x * x + y * y + z * z + 1e-8f);
    w *= iq; x *= iq; y *= iq; z *= iq;
    float* R = rotb + (size_t)bl * 9;
    R[0] = 1.f - 2.f * (y * y + z * z); R[1] = 2.f * (x * y - w * z); R[2] = 2.f * (x * z + w * y);
    R[3] = 2.f * (x * y + w * z); R[4] = 1.f - 2.f * (x * x + z * z); R[5] = 2.f * (y * z - w * x);
    R[6] = 2.f * (x * z - w * y); R[7] = 2.f * (y * z + w * x); R[8] = 1.f - 2.f * (x * x + y * y);
  }
}

// ---------- MFMA bf16 GEMM: C[M,N](fp32) = A[M,K](fp32) @ Bt[N,K](bf16)^T (+bias)(+relu)
__global__ __launch_bounds__(256) void gemm_mfma_k(const float* __restrict__ A, const short* __restrict__ Bt,
                                                   const float* __restrict__ bias, float* __restrict__ C,
                                                   int M, int N, int K, int relu) {
  __shared__ __align__(16) short As[128 * 40];
  __shared__ __align__(16) short Bs[128 * 40];
  const int tid = threadIdx.x;
  const int wid = tid >> 6, lane = tid & 63;
  const int c15 = lane & 15, q = lane >> 4;
  const int bm = blockIdx.y, bn = blockIdx.x;
  const int m_wave = (wid & 1) * 64, n_wave = (wid >> 1) * 64;
  const float* Ab = A + (size_t)(bm * 128) * K;
  const short* Bb = Bt + (size_t)(bn * 128) * K;

  f4v acc[4][4];
#pragma unroll
  for (int mi = 0; mi < 4; mi++)
#pragma unroll
    for (int ni = 0; ni < 4; ni++) acc[mi][ni] = (f4v){0.f, 0.f, 0.f, 0.f};

  for (int k0 = 0; k0 < K; k0 += 32) {
    __syncthreads();
#pragma unroll
    for (int e = 0; e < 4; e++) {
      const int slot = tid + e * 256;
      const int m = slot >> 3, k4 = (slot & 7) * 4;
      const float4 a = *(const float4*)(Ab + (size_t)m * K + k0 + k4);
      short pk[4] = {f2bs(a.x), f2bs(a.y), f2bs(a.z), f2bs(a.w)};
      *(int2*)&As[m * 40 + k4] = *(const int2*)pk;
    }
#pragma unroll
    for (int e = 0; e < 2; e++) {
      const int slot = tid + e * 256;
      const int n = slot >> 2, k8 = (slot & 3) * 8;
      *(int4*)&Bs[n * 40 + k8] = *(const int4*)(Bb + (size_t)n * K + k0 + k8);
    }
    __syncthreads();
    s8v Af[4], Bf[4];
#pragma unroll
    for (int mi = 0; mi < 4; mi++) Af[mi] = *(const s8v*)&As[(m_wave + mi * 16 + c15) * 40 + q * 8];
#pragma unroll
    for (int ni = 0; ni < 4; ni++) Bf[ni] = *(const s8v*)&Bs[(n_wave + ni * 16 + c15) * 40 + q * 8];
#pragma unroll
    for (int mi = 0; mi < 4; mi++)
#pragma unroll
      for (int ni = 0; ni < 4; ni++)
        acc[mi][ni] = __builtin_amdgcn_mfma_f32_16x16x32_bf16(Af[mi], Bf[ni], acc[mi][ni], 0, 0, 0);
  }
#pragma unroll
  for (int mi = 0; mi < 4; mi++) {
#pragma unroll
    for (int r = 0; r < 4; r++) {
      const int row = bm * 128 + m_wave + mi * 16 + q * 4 + r;
      float* Cr = C + (size_t)row * N + bn * 128 + n_wave;
#pragma unroll
      for (int ni = 0; ni < 4; ni++) {
        const int col = bn * 128 + n_wave + ni * 16 + c15;
        float v = acc[mi][ni][r];
        if (bias != nullptr) v += bias[col];
        if (relu) v = fmaxf(v, 0.f);
        Cr[ni * 16 + c15] = v;
      }
    }
  }
}

// ---------- assemble (wave per residue): Q/K bf16 [bh][L][96], V^T bf16 [bh][160][L] ----------
__global__ __launch_bounds__(64) void assemble_k(const float* __restrict__ proj, const float* __restrict__ rotb,
                                                 const float* __restrict__ trans, const void* __restrict__ z1raw,
                                                 const void* __restrict__ z2raw, const float* __restrict__ Wzq,
                                                 const float* __restrict__ Wzk, const float* __restrict__ headw,
                                                 const int* __restrict__ flagp, short* __restrict__ Qb,
                                                 short* __restrict__ Kb, short* __restrict__ Vtb) {
  __shared__ float qt[8][16], kt[8][16];
  const int bl = blockIdx.x, lane = threadIdx.x;
  const int h = lane >> 3, sub = lane & 7;
  const int flag = flagp[0];
  const float* pr = proj + (size_t)bl * NPROJ;
  const float* R = rotb + (size_t)bl * 9;
  const float txx = trans[bl * 3 + 0], tyy = trans[bl * 3 + 1], tzz = trans[bl * 3 + 2];
  float gamma;
  { const float w = headw[h]; gamma = (w > 20.f) ? w : log1pf(__expf(w)); }
  const float wL = 0.57735026918962576f;  // sqrt(1/3)
  const float wC = 0.23570226039551584f;  // sqrt(2/(9*4))
  const float ch = wL * wC * 0.5f * gamma;
  const float qscale = wL * 0.125f;       // wL / sqrt(64)

  // z-dot split across the 8 lanes of each h-group
  float zq0 = 0.f, zq1 = 0.f, zk0 = 0.f, zk1 = 0.f;
  const size_t zbase = (size_t)bl * 256;
  for (int zz = sub; zz < 128; zz += 8) {
    const float a0 = ldraw(z1raw, zbase + zz, flag);
    const float a1 = ldraw(z1raw, zbase + 128 + zz, flag);
    const float wq = Wzq[zz * 8 + h], wk = Wzk[zz * 8 + h];
    zq0 = fmaf(a0, wq, zq0); zq1 = fmaf(a1, wq, zq1);
    zk0 = fmaf(a0, wk, zk0); zk1 = fmaf(a1, wk, zk1);
  }
#pragma unroll
  for (int o = 1; o < 8; o <<= 1) {
    zq0 += __shfl_xor(zq0, o, 64); zq1 += __shfl_xor(zq1, o, 64);
    zk0 += __shfl_xor(zk0, o, 64); zk1 += __shfl_xor(zk1, o, 64);
  }

  const int b = bl >> 10, l = bl & 1023;
  const int bh = b * NH + h;
  const size_t row = (size_t)bh * LL + l;
  short* Q = Qb + row * QDP;
  short* Kx = Kb + row * QDP;

  // main 64 cols: each lane packs 8
  {
    const float* ps = pr + h * 64 + sub * 8;
    const float4 a0 = ((const float4*)ps)[0], a1 = ((const float4*)ps)[1];
    int4 qi;
    qi.x = packbf(a0.x * qscale, a0.y * qscale); qi.y = packbf(a0.z * qscale, a0.w * qscale);
    qi.z = packbf(a1.x * qscale, a1.y * qscale); qi.w = packbf(a1.z * qscale, a1.w * qscale);
    ((int4*)Q)[sub] = qi;
    const float* pk = pr + 512 + h * 64 + sub * 8;
    const float4 b0 = ((const float4*)pk)[0], b1 = ((const float4*)pk)[1];
    int4 ki;
    ki.x = packbf(b0.x, b0.y); ki.y = packbf(b0.z, b0.w);
    ki.z = packbf(b1.x, b1.y); ki.w = packbf(b1.z, b1.w);
    ((int4*)Kx)[sub] = ki;
    const float* pv = pr + 1024 + h * 64 + sub * 8;
#pragma unroll
    for (int e = 0; e < 8; e++)
      Vtb[((size_t)bh * VDP + sub * 8 + e) * LL + l] = f2bs(pv[e]);
  }

  // points: lanes 0-3 -> q-points, 4-7 -> k-points
  {
    const float* pp = pr + ((sub < 4) ? 1536 : 1632) + h * 12 + (sub & 3) * 3;
    const float gx = R[0] * pp[0] + R[1] * pp[1] + R[2] * pp[2] + txx;
    const float gy = R[3] * pp[0] + R[4] * pp[1] + R[5] * pp[2] + tyy;
    const float gz = R[6] * pp[0] + R[7] * pp[1] + R[8] * pp[2] + tzz;
    float nrm = gx * gx + gy * gy + gz * gz;
    nrm += __shfl_xor(nrm, 1, 64);
    nrm += __shfl_xor(nrm, 2, 64);
    const float other = __shfl_xor(nrm, 4, 64);
    const float qn = (sub < 4) ? nrm : other;
    const float kn = (sub < 4) ? other : nrm;
    if (sub < 4) {
      qt[h][2 + sub * 3 + 0] = 2.f * ch * gx;
      qt[h][2 + sub * 3 + 1] = 2.f * ch * gy;
      qt[h][2 + sub * 3 + 2] = 2.f * ch * gz;
    } else {
      kt[h][2 + (sub - 4) * 3 + 0] = gx;
      kt[h][2 + (sub - 4) * 3 + 1] = gy;
      kt[h][2 + (sub - 4) * 3 + 2] = gz;
    }
    if (sub == 0) {
      qt[h][0] = wL * zq0; qt[h][1] = wL * zq1; qt[h][14] = -ch * qn; qt[h][15] = 1.f;
      kt[h][0] = zk0;      kt[h][1] = zk1;      kt[h][14] = 1.f;      kt[h][15] = -ch * kn;
    }
  }
  // single wave: LDS RAW handled by compiler waitcnt; pack tails
  {
    int4 z4; z4.x = 0; z4.y = 0; z4.z = 0; z4.w = 0;
    if (sub < 2) {
      const float* s4 = &qt[h][sub * 8];
      int4 qi;
      qi.x = packbf(s4[0], s4[1]); qi.y = packbf(s4[2], s4[3]);
      qi.z = packbf(s4[4], s4[5]); qi.w = packbf(s4[6], s4[7]);
      ((int4*)Q)[8 + sub] = qi;
    } else if (sub < 4) {
      const float* s4 = &kt[h][(sub - 2) * 8];
      int4 ki;
      ki.x = packbf(s4[0], s4[1]); ki.y = packbf(s4[2], s4[3]);
      ki.z = packbf(s4[4], s4[5]); ki.w = packbf(s4[6], s4[7]);
      ((int4*)Kx)[8 + sub - 2] = ki;
    } else if (sub == 4) ((int4*)Q)[10] = z4;
    else if (sub == 5) ((int4*)Q)[11] = z4;
    else if (sub == 6) ((int4*)Kx)[10] = z4;
    else ((int4*)Kx)[11] = z4;
  }
  // V points (lane sub -> v-point sub)
  {
    const float* pv3 = pr + 1728 + h * 24 + sub * 3;
    const float gx = R[0] * pv3[0] + R[1] * pv3[1] + R[2] * pv3[2] + txx;
    const float gy = R[3] * pv3[0] + R[4] * pv3[1] + R[5] * pv3[2] + tyy;
    const float gz = R[6] * pv3[0] + R[7] * pv3[1] + R[8] * pv3[2] + tzz;
    const int c = 64 + sub * 3;
    Vtb[((size_t)bh * VDP + c + 0) * LL + l] = f2bs(gx);
    Vtb[((size_t)bh * VDP + c + 1) * LL + l] = f2bs(gy);
    Vtb[((size_t)bh * VDP + c + 2) * LL + l] = f2bs(gz);
  }
  // V z2 cols 88..151
  {
    const size_t z2base = ((size_t)bl * NH + h) * 64 + sub * 8;
#pragma unroll
    for (int e = 0; e < 8; e++)
      Vtb[((size_t)bh * VDP + 88 + sub * 8 + e) * LL + l] = f2bs(ldraw(z2raw, z2base + e, flag));
    Vtb[((size_t)bh * VDP + 152 + sub) * LL + l] = 0;
  }
}

// ---------- MFMA flash attention v3: 8 waves, j-split halves, register prefetch pipeline ----------
// launch_bounds(512, 2): grid is 512 blocks on 256 CUs -> 2 blocks/CU is the grid-imposed cap,
// so the 128-VGPR budget costs no occupancy (the (512,4)/64-VGPR bound caused scratch spills).
__global__ __launch_bounds__(512, 2) void attn_k(const short* __restrict__ Qb, const short* __restrict__ Kb,
                                                 const short* __restrict__ Vtb, const float* __restrict__ maskF,
                                                 float* __restrict__ Oext) {
  __shared__ __align__(16) short smem[26624];   // 53,248 B
  short* Ks = smem;                    // [2][32][104]
  short* Vs = smem + 6656;             // [2][160][40]
  short* Ps = smem + 19456;            // [8][16][40]
  float* Msl = (float*)(smem + 24576); // [1024] full mask row
  const int tid = threadIdx.x;
  const int wid = tid >> 6, lane = tid & 63;
  const int c15 = lane & 15, q = lane >> 4;
  const int blk = blockIdx.x;
  const int bh = blk & 31, qt2 = blk >> 5;      // same-bh blocks share blk%8 -> same XCD
  const int b = bh >> 3, h = bh & 7;
  const int half = wid >> 2, mw = wid & 3;
  const int i0 = qt2 * 64 + mw * 16;

  const short* Kbase = Kb + (size_t)bh * LL * QDP;
  const short* Vbase = Vtb + (size_t)bh * VDP * LL;

  s8v Qa[3];
  const short* Qrow = Qb + ((size_t)bh * LL + i0 + c15) * QDP;
#pragma unroll
  for (int kc = 0; kc < 3; kc++) Qa[kc] = *(const s8v*)(Qrow + kc * 32 + q * 8);

  f4v Of[10];
#pragma unroll
  for (int vt = 0; vt < 10; vt++) Of[vt] = (f4v){0.f, 0.f, 0.f, 0.f};
  float mold[4] = {-1e30f, -1e30f, -1e30f, -1e30f};
  float lsum[4] = {0.f, 0.f, 0.f, 0.f};

  // mask preload (whole row)
  Msl[tid] = maskF[b * LL + tid];
  Msl[tid + 512] = maskF[b * LL + tid + 512];

  // staging index decomposition (fixed per thread)
  const int khs0 = tid / 384;
  const int kv0 = tid - khs0 * 384;
  const int krr0 = kv0 / 12, kcc0 = kv0 - krr0 * 12;
  int khs1 = 0, krr1 = 0, kcc1 = 0;
  if (tid < 256) { const int u = tid + 512; khs1 = u / 384; const int v2 = u - khs1 * 384; krr1 = v2 / 12; kcc1 = v2 - krr1 * 12; }
  const int vhs0 = tid / 640; const int vv0 = tid - vhs0 * 640; const int vcc0 = vv0 >> 2, vp0 = vv0 & 3;
  const int vhs1 = (tid + 512) / 640; const int vv1 = (tid + 512) - vhs1 * 640; const int vcc1 = vv1 >> 2, vp1 = vv1 & 3;
  int vhs2 = 0, vcc2 = 0, vp2 = 0;
  if (tid < 256) { const int u = tid + 1024; vhs2 = u / 640; const int v2 = u - vhs2 * 640; vcc2 = v2 >> 2; vp2 = v2 & 3; }

  // prefetch tile 0
  int4 kr0, kr1, vr0, vr1, vr2;
  kr0 = *(const int4*)(Kbase + (size_t)(khs0 * 512 + krr0) * QDP + kcc0 * 8);
  if (tid < 256) kr1 = *(const int4*)(Kbase + (size_t)(khs1 * 512 + krr1) * QDP + kcc1 * 8);
  vr0 = *(const int4*)(Vbase + (size_t)vcc0 * LL + vhs0 * 512 + vp0 * 8);
  vr1 = *(const int4*)(Vbase + (size_t)vcc1 * LL + vhs1 * 512 + vp1 * 8);
  if (tid < 256) vr2 = *(const int4*)(Vbase + (size_t)vcc2 * LL + vhs2 * 512 + vp2 * 8);

  short* Ksl = Ks + half * 3328;
  short* Vsl = Vs + half * 6400;
  short* Pl = Ps + wid * 640;

  for (int jt = 0; jt < 16; jt++) {
    const int j0 = jt * 32;
    __syncthreads();   // prior compute done (jt=0: also orders Msl writes)
    *(int4*)&Ks[khs0 * 3328 + krr0 * 104 + kcc0 * 8] = kr0;
    if (tid < 256) *(int4*)&Ks[khs1 * 3328 + krr1 * 104 + kcc1 * 8] = kr1;
    *(int4*)&Vs[vhs0 * 6400 + vcc0 * 40 + vp0 * 8] = vr0;
    *(int4*)&Vs[vhs1 * 6400 + vcc1 * 40 + vp1 * 8] = vr1;
    if (tid < 256) *(int4*)&Vs[vhs2 * 6400 + vcc2 * 40 + vp2 * 8] = vr2;
    __syncthreads();
    if (jt < 15) {     // prefetch next tile into registers (overlaps compute)
      const int j0n = j0 + 32;
      kr0 = *(const int4*)(Kbase + (size_t)(khs0 * 512 + j0n + krr0) * QDP + kcc0 * 8);
      if (tid < 256) kr1 = *(const int4*)(Kbase + (size_t)(khs1 * 512 + j0n + krr1) * QDP + kcc1 * 8);
      vr0 = *(const int4*)(Vbase + (size_t)vcc0 * LL + vhs0 * 512 + j0n + vp0 * 8);
      vr1 = *(const int4*)(Vbase + (size_t)vcc1 * LL + vhs1 * 512 + j0n + vp1 * 8);
      if (tid < 256) vr2 = *(const int4*)(Vbase + (size_t)vcc2 * LL + vhs2 * 512 + j0n + vp2 * 8);
    }

    f4v Sf0 = (f4v){0.f, 0.f, 0.f, 0.f}, Sf1 = (f4v){0.f, 0.f, 0.f, 0.f};
#pragma unroll
    for (int kc = 0; kc < 3; kc++) {
      const s8v K0 = *(const s8v*)&Ksl[c15 * 104 + kc * 32 + q * 8];
      const s8v K1 = *(const s8v*)&Ksl[(16 + c15) * 104 + kc * 32 + q * 8];
      Sf0 = __builtin_amdgcn_mfma_f32_16x16x32_bf16(Qa[kc], K0, Sf0, 0, 0, 0);
      Sf1 = __builtin_amdgcn_mfma_f32_16x16x32_bf16(Qa[kc], K1, Sf1, 0, 0, 0);
    }
    const float mv0 = Msl[half * 512 + j0 + c15];
    const float mv1 = Msl[half * 512 + j0 + 16 + c15];
    float lg0[4], lg1[4], tm[4], p0[4], p1[4];
#pragma unroll
    for (int r = 0; r < 4; r++) {
      lg0[r] = (mv0 > 0.f) ? Sf0[r] : -1e9f;
      lg1[r] = (mv1 > 0.f) ? Sf1[r] : -1e9f;
      tm[r] = fmaxf(lg0[r], lg1[r]);
    }
#pragma unroll
    for (int r = 0; r < 4; r++) {
      tm[r] = fmaxf(tm[r], __shfl_xor(tm[r], 1, 64));
      tm[r] = fmaxf(tm[r], __shfl_xor(tm[r], 2, 64));
      tm[r] = fmaxf(tm[r], __shfl_xor(tm[r], 4, 64));
      tm[r] = fmaxf(tm[r], __shfl_xor(tm[r], 8, 64));
    }
    const bool need = (tm[0] > mold[0]) | (tm[1] > mold[1]) | (tm[2] > mold[2]) | (tm[3] > mold[3]);
    if (__any(need)) {
      float al[4];
#pragma unroll
      for (int r = 0; r < 4; r++) {
        const float mn = fmaxf(mold[r], tm[r]);
        al[r] = __expf(mold[r] - mn);
        mold[r] = mn;
        p0[r] = __expf(lg0[r] - mn);
        p1[r] = __expf(lg1[r] - mn);
        lsum[r] = lsum[r] * al[r] + p0[r] + p1[r];
      }
#pragma unroll
      for (int vt = 0; vt < 10; vt++) {
#pragma unroll
        for (int r = 0; r < 4; r++) Of[vt][r] *= al[r];
      }
    } else {
#pragma unroll
      for (int r = 0; r < 4; r++) {
        p0[r] = __expf(lg0[r] - mold[r]);
        p1[r] = __expf(lg1[r] - mold[r]);
        lsum[r] += p0[r] + p1[r];
      }
    }
#pragma unroll
    for (int r = 0; r < 4; r++) {
      Pl[(q * 4 + r) * 40 + c15] = f2bs(p0[r]);
      Pl[(q * 4 + r) * 40 + 16 + c15] = f2bs(p1[r]);
    }
    const s8v Pa = *(const s8v*)&Pl[c15 * 40 + q * 8];
#pragma unroll
    for (int vt = 0; vt < 10; vt++) {
      const s8v Vf = *(const s8v*)&Vsl[(vt * 16 + c15) * 40 + q * 8];
      Of[vt] = __builtin_amdgcn_mfma_f32_16x16x32_bf16(Pa, Vf, Of[vt], 0, 0, 0);
    }
  }
#pragma unroll
  for (int r = 0; r < 4; r++) {
    lsum[r] += __shfl_xor(lsum[r], 1, 64);
    lsum[r] += __shfl_xor(lsum[r], 2, 64);
    lsum[r] += __shfl_xor(lsum[r], 4, 64);
    lsum[r] += __shfl_xor(lsum[r], 8, 64);
  }
  // merge halves through LDS
  float* Obuf = (float*)smem;              // [4][16][160] = 40,960 B
  float* Mbuf = (float*)(smem + 20480);    // [64]
  float* Lbuf = Mbuf + 64;                 // [64]
  __syncthreads();
  if (half == 1) {
#pragma unroll
    for (int r = 0; r < 4; r++) {
      const int rowi = mw * 16 + q * 4 + r;
#pragma unroll
      for (int vt = 0; vt < 10; vt++) Obuf[rowi * 160 + vt * 16 + c15] = Of[vt][r];
      if (c15 == 0) { Mbuf[rowi] = mold[r]; Lbuf[rowi] = lsum[r]; }
    }
  }
  __syncthreads();
  if (half == 0) {
#pragma unroll
    for (int r = 0; r < 4; r++) {
      const int rowi = mw * 16 + q * 4 + r;
      const float m2 = Mbuf[rowi], l2 = Lbuf[rowi];
      const float mx = fmaxf(mold[r], m2);
      const float a1 = __expf(mold[r] - mx), a2 = __expf(m2 - mx);
      const float inv = 1.f / (lsum[r] * a1 + l2 * a2);
      const int i = i0 + q * 4 + r;
      float* Or = Oext + ((size_t)(b * LL + i) * NH + h) * VDP;
#pragma unroll
      for (int vt = 0; vt < 10; vt++)
        Or[vt * 16 + c15] = (Of[vt][r] * a1 + Obuf[rowi * 160 + vt * 16 + c15] * a2) * inv;
    }
  }
}

// ---------- feat assembly (wave per residue) ----------
__global__ __launch_bounds__(64) void feat_k(const float* __restrict__ Oext, const float* __restrict__ rotb,
                                             const float* __restrict__ trans, float* __restrict__ feat) {
  const int bl = blockIdx.x, lane = threadIdx.x;
  const int h = lane >> 3, sub = lane & 7;
  const float* O = Oext + ((size_t)bl * 8 + h) * VDP;
  float* f = feat + (size_t)bl * FEATD;
  {
    const float4 a0 = ((const float4*)(O + sub * 8))[0], a1 = ((const float4*)(O + sub * 8))[1];
    ((float4*)(f + h * 64 + sub * 8))[0] = a0;
    ((float4*)(f + h * 64 + sub * 8))[1] = a1;
    const float4 z0 = ((const float4*)(O + 88 + sub * 8))[0], z1 = ((const float4*)(O + 88 + sub * 8))[1];
    ((float4*)(f + 768 + h * 64 + sub * 8))[0] = z0;
    ((float4*)(f + 768 + h * 64 + sub * 8))[1] = z1;
  }
  const float* R = rotb + (size_t)bl * 9;
  const float txx = trans[bl * 3 + 0], tyy = trans[bl * 3 + 1], tzz = trans[bl * 3 + 2];
  {
    const float dx = O[64 + sub * 3 + 0] - txx;
    const float dy = O[64 + sub * 3 + 1] - tyy;
    const float dz = O[64 + sub * 3 + 2] - tzz;
    const float lx = R[0] * dx + R[3] * dy + R[6] * dz;   // R^T * diff
    const float ly = R[1] * dx + R[4] * dy + R[7] * dz;
    const float lz = R[2] * dx + R[5] * dy + R[8] * dz;
    f[512 + h * 24 + sub * 3 + 0] = lx;
    f[512 + h * 24 + sub * 3 + 1] = ly;
    f[512 + h * 24 + sub * 3 + 2] = lz;
    f[704 + h * 8 + sub] = sqrtf(lx * lx + ly * ly + lz * lz + 1e-8f);
  }
}

// ---------- LayerNorm(x + resid) (one wave per row) ----------
__global__ __launch_bounds__(64) void ln_k(const float* __restrict__ x, const float* __restrict__ resid,
                                           const float* __restrict__ g, const float* __restrict__ bta,
                                           float* __restrict__ out) {
  const int row = blockIdx.x, t = threadIdx.x;
  const float* xr = x + (size_t)row * CSD;
  const float* rr = resid + (size_t)row * CSD;
  float v[6];
  float s = 0.f;
#pragma unroll
  for (int e = 0; e < 6; e++) {
    const int c = t + e * 64;
    v[e] = xr[c] + rr[c];
    s += v[e];
  }
  s = wredf(s);
  const float mu = s * (1.f / 384.f);
  float var = 0.f;
#pragma unroll
  for (int e = 0; e < 6; e++) { const float d = v[e] - mu; var = fmaf(d, d, var); }
  var = wredf(var) * (1.f / 384.f);
  const float inv = rsqrtf(var + 1e-5f);
#pragma unroll
  for (int e = 0; e < 6; e++) {
    const int c = t + e * 64;
    out[(size_t)row * CSD + c] = (v[e] - mu) * inv * g[c] + bta[c];
  }
}

// ---------- fused tail LN + backbone update + mHC combine ----------
__global__ __launch_bounds__(64) void lnfinal_k(const float* __restrict__ x /*x3*/, const float* __restrict__ resid /*s1*/,
                                                const float* __restrict__ g, const float* __restrict__ bta,
                                                const float* __restrict__ sF, const float* __restrict__ rotb,
                                                const float* __restrict__ trans, const float* __restrict__ hpost,
                                                const float* __restrict__ rowsum, const float* __restrict__ Wbb,
                                                const float* __restrict__ bbb, const int* __restrict__ flagp,
                                                void* __restrict__ outv) {
  const int bl = blockIdx.x, t = threadIdx.x;
  const int flag = flagp[0];
  bf16* outb = (bf16*)outv;
  float* outf = (float*)outv;
  // --- LN(x + resid) -> si values in registers ---
  const float* xr = x + (size_t)bl * CSD;
  const float* rr = resid + (size_t)bl * CSD;
  float v[6];
  float s = 0.f;
#pragma unroll
  for (int e = 0; e < 6; e++) {
    const int c = t + e * 64;
    v[e] = xr[c] + rr[c];
    s += v[e];
  }
  s = wredf(s);
  const float mu = s * (1.f / 384.f);
  float var = 0.f;
#pragma unroll
  for (int e = 0; e < 6; e++) { const float d = v[e] - mu; var = fmaf(d, d, var); }
  var = wredf(var) * (1.f / 384.f);
  const float inv = rsqrtf(var + 1e-5f);
  float si6[6];
#pragma unroll
  for (int e = 0; e < 6; e++) {
    const int c = t + e * 64;
    si6[e] = (v[e] - mu) * inv * g[c] + bta[c];
  }
  // --- backbone update ---
  float d6[6] = {0.f, 0.f, 0.f, 0.f, 0.f, 0.f};
#pragma unroll
  for (int e = 0; e < 6; e++) {
    const int c = t + e * 64;
#pragma unroll
    for (int u = 0; u < 6; u++) d6[u] = fmaf(si6[e], Wbb[c * 6 + u], d6[u]);
  }
#pragma unroll
  for (int u = 0; u < 6; u++) d6[u] = wredf(d6[u]);
  float upd[6];
#pragma unroll
  for (int u = 0; u < 6; u++) upd[u] = d6[u] + bbb[u];
  const float* R = rotb + (size_t)bl * 9;
  if (t == 0) {
    float w = 1.f, x2 = upd[0], y = upd[1], z = upd[2];
    const float iq = rsqrtf(w * w + x2 * x2 + y * y + z * z + 1e-8f);
    w *= iq; x2 *= iq; y *= iq; z *= iq;
    const float Ru[9] = {1.f - 2.f * (y * y + z * z), 2.f * (x2 * y - w * z), 2.f * (x2 * z + w * y),
                         2.f * (x2 * y + w * z), 1.f - 2.f * (x2 * x2 + z * z), 2.f * (y * z - w * x2),
                         2.f * (x2 * z - w * y), 2.f * (y * z + w * x2), 1.f - 2.f * (x2 * x2 + y * y)};
#pragma unroll
    for (int i = 0; i < 3; i++)
#pragma unroll
      for (int j = 0; j < 3; j++) {
        const float rv = R[i * 3 + 0] * Ru[0 + j] + R[i * 3 + 1] * Ru[3 + j] + R[i * 3 + 2] * Ru[6 + j];
        const size_t o = OUT_ROT + (size_t)bl * 9 + i * 3 + j;
        if (flag) outb[o] = __float2bfloat16(rv); else outf[o] = rv;
      }
#pragma unroll
    for (int i = 0; i < 3; i++) {
      const float tv = R[i * 3 + 0] * upd[3] + R[i * 3 + 1] * upd[4] + R[i * 3 + 2] * upd[5] + trans[bl * 3 + i];
      const size_t o = OUT_TR + (size_t)bl * 3 + i;
      if (flag) outb[o] = __float2bfloat16(tv); else outf[o] = tv;
    }
  }
  // --- mHC combine ---
  const float hp0 = hpost[bl * 4 + 0], hp1 = hpost[bl * 4 + 1], hp2 = hpost[bl * 4 + 2], hp3 = hpost[bl * 4 + 3];
  const float rs0 = rowsum[bl * 4 + 0], rs1 = rowsum[bl * 4 + 1], rs2 = rowsum[bl * 4 + 2], rs3 = rowsum[bl * 4 + 3];
  const float* sr = sF + (size_t)bl * CSD;
#pragma unroll
  for (int e = 0; e < 6; e++) {
    const int c = t + e * 64;
    const float sv = sr[c], sp = si6[e];
    const size_t base = (size_t)bl * 4 * CSD + c;
    const float o0 = rs0 * sv + hp0 * sp;
    const float o1 = rs1 * sv + hp1 * sp;
    const float o2 = rs2 * sv + hp2 * sp;
    const float o3 = rs3 * sv + hp3 * sp;
    if (flag) {
      outb[base + 0 * CSD] = __float2bfloat16(o0);
      outb[base + 1 * CSD] = __float2bfloat16(o1);
      outb[base + 2 * CSD] = __float2bfloat16(o2);
      outb[base + 3 * CSD] = __float2bfloat16(o3);
    } else {
      outf[base + 0 * CSD] = o0;
      outf[base + 1 * CSD] = o1;
      outf[base + 2 * CSD] = o2;
      outf[base + 3 * CSD] = o3;
    }
  }
}

extern "C" void kernel_launch(void* const* d_in, const int* in_sizes, int n_in,
                              void* d_out, int out_size, void* d_ws, size_t ws_size,
                              hipStream_t stream) {
  float* ws = (float*)d_ws;
  int* flag = (int*)(ws + WS_FLAG);

  P36 ptrs;
  for (int i = 0; i < 36; i++) ptrs.p[i] = d_in[i];

  float* sF     = ws + OFF_S;
  float* WpostR = ws + WS_WPOSTR;
  float* WresR  = ws + WS_WRESR;
  float* hpost  = ws + WS_HPOST;
  float* rowsum = ws + WS_ROWSUM;
  float* rotb   = ws + WS_ROTB;
  short* WcatT  = (short*)(ws + WS_WCATT);
  short* WoT    = (short*)(ws + WS_WOT);
  short* Wt1T   = (short*)(ws + WS_WT1T);
  short* Wt2T   = (short*)(ws + WS_WT2T);
  short* Wt3T   = (short*)(ws + WS_WT3T);
  float* proj   = ws + WS_PROJ;
  short* Qb     = (short*)(ws + WS_QB);
  short* Kb     = (short*)(ws + WS_KB);
  short* Vtb    = (short*)(ws + WS_VT);
  float* Oext   = ws + WS_PROJ;               // overlay (proj dead after assemble)
  float* featb  = ws + WS_QB;                 // overlay, spans QB..VT (dead after attn)
  float* x1s1   = ws + WS_PROJ;               // overlay (Oext dead after feat_k)
  float* t1b    = ws + WS_PROJ + 1572864;
  float* t2b    = ws + WS_PROJ + 3145728;
  float* x3     = ws + WS_PROJ + 4718592;

  detect_k<<<1, 64, 0, stream>>>((const unsigned int*)d_in[5], flag);
  cvtall_k<<<(IN_END + 255) / 256, 256, 0, stream>>>(ptrs, ws, flag);
  wprep_k<<<1632, 256, 0, stream>>>(ws, (short*)ws);
  wreduce_k<<<24, 256, 0, stream>>>(ws + OFF_WPOST, ws + OFF_WRES, WpostR, WresR);
  mhc_k<<<BL, 64, 0, stream>>>(sF, ws + OFF_QUAT, ws + OFF_BPOST, ws + OFF_BRES, ws + OFF_ALPHA,
                               WpostR, WresR, hpost, rowsum, rotb);
  gemm_mfma_k<<<dim3(15, 32), 256, 0, stream>>>(sF, WcatT, nullptr, proj, BL, NPROJ, CSD, 0);
  assemble_k<<<BL, 64, 0, stream>>>(proj, rotb, ws + OFF_TRANS, d_in[1], d_in[2],
                                    ws + OFF_WZQ, ws + OFF_WZK, ws + OFF_HEADW, flag, Qb, Kb, Vtb);
  attn_k<<<512, 512, 0, stream>>>(Qb, Kb, Vtb, ws + OFF_MASK, Oext);
  feat_k<<<BL, 64, 0, stream>>>(Oext, rotb, ws + OFF_TRANS, featb);
  gemm_mfma_k<<<dim3(3, 32), 256, 0, stream>>>(featb, WoT, ws + OFF_BO, x1s1, BL, CSD, FEATD, 0);
  ln_k<<<BL, 64, 0, stream>>>(x1s1, sF, ws + OFF_LN1G, ws + OFF_LN1B, x1s1);                   // s1
  gemm_mfma_k<<<dim3(3, 32), 256, 0, stream>>>(x1s1, Wt1T, ws + OFF_BT1, t1b, BL, CSD, CSD, 1);
  gemm_mfma_k<<<dim3(3, 32), 256, 0, stream>>>(t1b, Wt2T, ws + OFF_BT2, t2b, BL, CSD, CSD, 1);
  gemm_mfma_k<<<dim3(3, 32), 256, 0, stream>>>(t2b, Wt3T, ws + OFF_BT3, x3, BL, CSD, CSD, 0);
  lnfinal_k<<<BL, 64, 0, stream>>>(x3, x1s1, ws + OFF_LNTG, ws + OFF_LNTB, sF, rotb,
                                   ws + OFF_TRANS, hpost, rowsum, ws + OFF_WBB, ws + OFF_BBB,
                                   flag, d_out);
}

// Round 9
// 459.522 us; speedup vs baseline: 1.2719x; 1.0495x over previous
//
#include <hip/hip_runtime.h>
#include <hip/hip_bf16.h>

typedef __hip_bfloat16 bf16;
typedef float f4v __attribute__((ext_vector_type(4)));
typedef short s8v __attribute__((ext_vector_type(8)));

#define CSD    384
#define LL     1024
#define NH     8
#define BL     4096        // B*L
#define NPROJ  1920
#define QDP    96          // 80 real ext-Q/K dims, padded to 96
#define VDP    160         // 152 real ext-V dims, padded to 160
#define FEATD  1280

// ---- fp32 input mirror (z1/z2 NOT mirrored — read raw in assemble) ----
#define OFF_S      0
#define OFF_QUAT   1572864
#define OFF_TRANS  1589248
#define OFF_MASK   1601536
#define OFF_BPOST  1605632
#define OFF_BRES   1605648
#define OFF_WPOST  1605664
#define OFF_WRES   1611808
#define OFF_ALPHA  1636384
#define OFF_WQ     1636400
#define OFF_WK     1833008
#define OFF_WV     2029616
#define OFF_WQP    2226224
#define OFF_WKP    2263088
#define OFF_WVP    2299952
#define OFF_WZQ    2373680
#define OFF_WZK    2374704
#define OFF_HEADW  2375728
#define OFF_WO     2375744
#define OFF_BO     2867264
#define OFF_LN1G   2867648
#define OFF_LN1B   2868032
#define OFF_WT1    2868416
#define OFF_BT1    3015872
#define OFF_WT2    3016256
#define OFF_BT2    3163712
#define OFF_WT3    3164096
#define OFF_BT3    3311552
#define OFF_LNTG   3311936
#define OFF_LNTB   3312320
#define OFF_WBB    3312704
#define OFF_BBB    3315008
#define IN_END     3315024

// ---- scratch (float offsets) ----
#define WS_FLAG    3315024
#define WS_WPOSTR  3315040
#define WS_WRESR   3316576
#define WS_HPOST   3322720
#define WS_ROWSUM  3339104
#define WS_ROTB    3355488
#define WS_WCATT   3392352      // bf16 Wcat^T [1920][384]
#define WS_WOT     3760992      // bf16 Wo^T [384][1280]
#define WS_WT1T    4006752
#define WS_WT2T    4080480
#define WS_WT3T    4154208
#define WS_PROJ    4227936      // 7,864,320 floats; overlays: Oext, x1s1/t1/t2/x3
#define WS_QB      12092256     // bf16 Q [32][1024][96]
#define WS_KB      13665120     // bf16 K [32][1024][96]
#define WS_VT      15237984     // bf16 V^T [32][160][1024]
#define WS_VROW    17859424     // bf16 V row-major [32][1024][160]
// end 20,480,864 floats = 81.9 MB

#define OUT_ROT 6291456
#define OUT_TR  6328320

#define NSEG 32

struct P36 { const void* p[36]; };

__device__ __forceinline__ float b2f(bf16 x) { return __bfloat162float(x); }

__device__ __forceinline__ short f2bs(float x) {
  unsigned u = __float_as_uint(x);
  u += 0x7FFFu + ((u >> 16) & 1u);
  return (short)(u >> 16);
}

__device__ __forceinline__ int packbf(float lo, float hi) {
  return (int)(unsigned short)f2bs(lo) | ((int)f2bs(hi) << 16);
}

__device__ __forceinline__ float ldraw(const void* p, size_t i, int flag) {
  return flag ? b2f(((const bf16*)p)[i]) : ((const float*)p)[i];
}

__device__ __forceinline__ float wredf(float v) {
#pragma unroll
  for (int o = 1; o < 64; o <<= 1) v += __shfl_xor(v, o, 64);
  return v;
}

// ---------- dtype detect ----------
__global__ void detect_k(const unsigned int* __restrict__ mask_raw, int* __restrict__ flag) {
  if (threadIdx.x == 0 && blockIdx.x == 0) flag[0] = (mask_raw[0] == 0x3F803F80u) ? 1 : 0;
}

// ---------- convert inputs (minus z1/z2) into fp32 mirror ----------
__global__ __launch_bounds__(256) void cvtall_k(P36 ptrs, float* __restrict__ dst, const int* __restrict__ flagp) {
  const int i = blockIdx.x * 256 + threadIdx.x;
  if (i >= IN_END) return;
  const int flag = flagp[0];
  const int seg_src_t[NSEG] = {0,3,4,5,7,8,10,11,12,13,14,15,16,17,18,19,20,21,22,23,24,25,26,27,28,29,30,31,32,33,34,35};
  const int seg_dst_t[NSEG] = {OFF_S,OFF_QUAT,OFF_TRANS,OFF_MASK,OFF_BPOST,OFF_BRES,OFF_WPOST,OFF_WRES,OFF_ALPHA,
                               OFF_WQ,OFF_WK,OFF_WV,OFF_WQP,OFF_WKP,OFF_WVP,OFF_WZQ,OFF_WZK,OFF_HEADW,
                               OFF_WO,OFF_BO,OFF_LN1G,OFF_LN1B,OFF_WT1,OFF_BT1,OFF_WT2,OFF_BT2,OFF_WT3,OFF_BT3,
                               OFF_LNTG,OFF_LNTB,OFF_WBB,OFF_BBB};
  const int seg_cnt_t[NSEG] = {1572864,16384,12288,4096,4,16,6144,24576,1,
                               196608,196608,196608,36864,36864,73728,1024,1024,8,
                               491520,384,384,384,147456,384,147456,384,147456,384,
                               384,384,2304,6};
  int off = i, cnt = seg_cnt_t[0];
  const void* sp = ptrs.p[0];
#pragma unroll
  for (int k = 1; k < NSEG; k++) {
    if (i >= seg_dst_t[k]) { off = i - seg_dst_t[k]; cnt = seg_cnt_t[k]; sp = ptrs.p[seg_src_t[k]]; }
  }
  float v = 0.f;
  if (off < cnt) v = flag ? b2f(((const bf16*)sp)[off]) : ((const float*)sp)[off];
  dst[i] = v;
}

// ---------- fused weight transposes: fp32 [K][N] -> bf16 [N][K], LDS 32x32 tiles ----------
__global__ __launch_bounds__(256) void wprep_k(const float* __restrict__ ws, short* __restrict__ wsS) {
  const int jobs_src[10] = {OFF_WQ, OFF_WK, OFF_WV, OFF_WQP, OFF_WKP, OFF_WVP, OFF_WO, OFF_WT1, OFF_WT2, OFF_WT3};
  const int jobs_dst[10] = {WS_WCATT*2, WS_WCATT*2 + 512*384, WS_WCATT*2 + 1024*384, WS_WCATT*2 + 1536*384,
                            WS_WCATT*2 + 1632*384, WS_WCATT*2 + 1728*384, WS_WOT*2, WS_WT1T*2, WS_WT2T*2, WS_WT3T*2};
  const int jobs_K[10] = {384,384,384,384,384,384,1280,384,384,384};
  const int jobs_N[10] = {512,512,512,96,96,192,384,384,384,384};
  const int jobs_t0[10] = {0,192,384,576,612,648,720,1200,1344,1488};
  const int t = blockIdx.x;
  int j = 0;
#pragma unroll
  for (int k = 1; k < 10; k++) if (t >= jobs_t0[k]) j = k;
  const int tl = t - jobs_t0[j];
  const int K = jobs_K[j], N = jobs_N[j];
  const int ntn = N >> 5;
  const int kt = tl / ntn, nt = tl - kt * ntn;
  const int k0 = kt * 32, n0 = nt * 32;
  const float* src = ws + jobs_src[j];
  short* dst = wsS + jobs_dst[j];
  __shared__ float T[32][36];
  {
    const int r = threadIdx.x >> 3, cq = (threadIdx.x & 7) * 4;
    const float4 a = *(const float4*)(src + (size_t)(k0 + r) * N + n0 + cq);
    T[r][cq] = a.x; T[r][cq + 1] = a.y; T[r][cq + 2] = a.z; T[r][cq + 3] = a.w;
  }
  __syncthreads();
  {
    const int n = threadIdx.x >> 3, kq = (threadIdx.x & 7) * 4;
    short pk4[4];
#pragma unroll
    for (int e = 0; e < 4; e++) pk4[e] = f2bs(T[kq + e][n]);
    *(int2*)(dst + (size_t)(n0 + n) * K + k0 + kq) = *(const int2*)pk4;
  }
}

// ---------- reduce W_post / W_res over stream blocks ----------
__global__ __launch_bounds__(256) void wreduce_k(const float* __restrict__ Wpost, const float* __restrict__ Wres,
                                                 float* __restrict__ WpostR, float* __restrict__ WresR) {
  int i = blockIdx.x * 256 + threadIdx.x;
  if (i < CSD * 4) {
    int c = i >> 2, n = i & 3;
    float s = 0.f;
#pragma unroll
    for (int blk = 0; blk < 4; blk++) s += Wpost[(blk * CSD + c) * 4 + n];
    WpostR[i] = s;
  }
  if (i < CSD * 16) {
    int c = i >> 4, n = i & 15;
    float s = 0.f;
#pragma unroll
    for (int blk = 0; blk < 4; blk++) s += Wres[(blk * CSD + c) * 16 + n];
    WresR[i] = s;
  }
}

// ---------- per-residue: H_post, sinkhorn row-sums, quat->rot ----------
__global__ __launch_bounds__(64) void mhc_k(const float* __restrict__ sF, const float* __restrict__ quat,
                                            const float* __restrict__ bpost, const float* __restrict__ bres,
                                            const float* __restrict__ alpha_p, const float* __restrict__ WpostR,
                                            const float* __restrict__ WresR, float* __restrict__ hpost,
                                            float* __restrict__ rowsum, float* __restrict__ rotb) {
  const int bl = blockIdx.x, t = threadIdx.x;
  const float* sr = sF + (size_t)bl * CSD;
  float ssq = 0.f, dp[4] = {0.f, 0.f, 0.f, 0.f}, dr[16];
#pragma unroll
  for (int n = 0; n < 16; n++) dr[n] = 0.f;
#pragma unroll
  for (int e = 0; e < 6; e++) {
    const int c = t + e * 64;
    const float sv = sr[c];
    ssq = fmaf(sv, sv, ssq);
#pragma unroll
    for (int n = 0; n < 4; n++) dp[n] = fmaf(sv, WpostR[c * 4 + n], dp[n]);
#pragma unroll
    for (int n = 0; n < 16; n++) dr[n] = fmaf(sv, WresR[c * 16 + n], dr[n]);
  }
  ssq = wredf(ssq);
#pragma unroll
  for (int n = 0; n < 4; n++) dp[n] = wredf(dp[n]);
#pragma unroll
  for (int n = 0; n < 16; n++) dr[n] = wredf(dr[n]);
  const float alpha = alpha_p[0];
  const float invn = rsqrtf(ssq * (1.f / 384.f) + 1e-6f);
  if (t == 0) {
#pragma unroll
    for (int n = 0; n < 4; n++) {
      const float x = bpost[n] + alpha * invn * dp[n];
      hpost[bl * 4 + n] = 2.f / (1.f + __expf(-x));
    }
    float M[16];
    float mx = -1e30f;
#pragma unroll
    for (int k = 0; k < 16; k++) { M[k] = bres[k] + alpha * invn * dr[k]; mx = fmaxf(mx, M[k]); }
#pragma unroll
    for (int k = 0; k < 16; k++) M[k] = __expf(M[k] - mx);
    for (int it = 0; it < 20; it++) {
#pragma unroll
      for (int r = 0; r < 4; r++) {
        const float s4 = M[r * 4] + M[r * 4 + 1] + M[r * 4 + 2] + M[r * 4 + 3];
        const float iv = 1.f / (s4 + 1e-8f);
        M[r * 4] *= iv; M[r * 4 + 1] *= iv; M[r * 4 + 2] *= iv; M[r * 4 + 3] *= iv;
      }
#pragma unroll
      for (int c2 = 0; c2 < 4; c2++) {
        const float s4 = M[c2] + M[4 + c2] + M[8 + c2] + M[12 + c2];
        const float iv = 1.f / (s4 + 1e-8f);
        M[c2] *= iv; M[4 + c2] *= iv; M[8 + c2] *= iv; M[12 + c2] *= iv;
      }
    }
#pragma unroll
    for (int r = 0; r < 4; r++)
      rowsum[bl * 4 + r] = M[r * 4] + M[r * 4 + 1] + M[r * 4 + 2] + M[r * 4 + 3];
  }
  if (t == 1) {
    float w = quat[bl * 4 + 0], x = quat[bl * 4 + 1];
    float y = quat[bl * 4 + 2], z = quat[bl * 4 + 3];
    const float iq = rsqrtf(w * w + x * x + y * y + z * z + 1e-8f);
    w *= iq; x *= iq; y *= iq; z *= iq;
    float* R = rotb + (size_t)bl * 9;
    R[0] = 1.f - 2.f * (y * y + z * z); R[1] = 2.f * (x * y - w * z); R[2] = 2.f * (x * z + w * y);
    R[3] = 2.f * (x * y + w * z); R[4] = 1.f - 2.f * (x * x + z * z); R[5] = 2.f * (y * z - w * x);
    R[6] = 2.f * (x * z - w * y); R[7] = 2.f * (y * z + w * x); R[8] = 1.f - 2.f * (x * x + y * y);
  }
}

// ---------- MFMA bf16 GEMM: C[M,N](fp32) = A[M,K](fp32) @ Bt[N,K](bf16)^T (+bias)(+relu)
__global__ __launch_bounds__(256) void gemm_mfma_k(const float* __restrict__ A, const short* __restrict__ Bt,
                                                   const float* __restrict__ bias, float* __restrict__ C,
                                                   int M, int N, int K, int relu) {
  __shared__ __align__(16) short As[128 * 40];
  __shared__ __align__(16) short Bs[128 * 40];
  const int tid = threadIdx.x;
  const int wid = tid >> 6, lane = tid & 63;
  const int c15 = lane & 15, q = lane >> 4;
  const int bm = blockIdx.y, bn = blockIdx.x;
  const int m_wave = (wid & 1) * 64, n_wave = (wid >> 1) * 64;
  const float* Ab = A + (size_t)(bm * 128) * K;
  const short* Bb = Bt + (size_t)(bn * 128) * K;

  f4v acc[4][4];
#pragma unroll
  for (int mi = 0; mi < 4; mi++)
#pragma unroll
    for (int ni = 0; ni < 4; ni++) acc[mi][ni] = (f4v){0.f, 0.f, 0.f, 0.f};

  for (int k0 = 0; k0 < K; k0 += 32) {
    __syncthreads();
#pragma unroll
    for (int e = 0; e < 4; e++) {
      const int slot = tid + e * 256;
      const int m = slot >> 3, k4 = (slot & 7) * 4;
      const float4 a = *(const float4*)(Ab + (size_t)m * K + k0 + k4);
      short pk[4] = {f2bs(a.x), f2bs(a.y), f2bs(a.z), f2bs(a.w)};
      *(int2*)&As[m * 40 + k4] = *(const int2*)pk;
    }
#pragma unroll
    for (int e = 0; e < 2; e++) {
      const int slot = tid + e * 256;
      const int n = slot >> 2, k8 = (slot & 3) * 8;
      *(int4*)&Bs[n * 40 + k8] = *(const int4*)(Bb + (size_t)n * K + k0 + k8);
    }
    __syncthreads();
    s8v Af[4], Bf[4];
#pragma unroll
    for (int mi = 0; mi < 4; mi++) Af[mi] = *(const s8v*)&As[(m_wave + mi * 16 + c15) * 40 + q * 8];
#pragma unroll
    for (int ni = 0; ni < 4; ni++) Bf[ni] = *(const s8v*)&Bs[(n_wave + ni * 16 + c15) * 40 + q * 8];
#pragma unroll
    for (int mi = 0; mi < 4; mi++)
#pragma unroll
      for (int ni = 0; ni < 4; ni++)
        acc[mi][ni] = __builtin_amdgcn_mfma_f32_16x16x32_bf16(Af[mi], Bf[ni], acc[mi][ni], 0, 0, 0);
  }
#pragma unroll
  for (int mi = 0; mi < 4; mi++) {
#pragma unroll
    for (int r = 0; r < 4; r++) {
      const int row = bm * 128 + m_wave + mi * 16 + q * 4 + r;
      float* Cr = C + (size_t)row * N + bn * 128 + n_wave;
#pragma unroll
      for (int ni = 0; ni < 4; ni++) {
        const int col = bn * 128 + n_wave + ni * 16 + c15;
        float v = acc[mi][ni][r];
        if (bias != nullptr) v += bias[col];
        if (relu) v = fmaxf(v, 0.f);
        Cr[ni * 16 + c15] = v;
      }
    }
  }
}

// ---------- assemble (wave per residue): Q/K bf16 [bh][L][96], V row-major bf16 [bh][L][160] ----------
__global__ __launch_bounds__(64) void assemble_k(const float* __restrict__ proj, const float* __restrict__ rotb,
                                                 const float* __restrict__ trans, const void* __restrict__ z1raw,
                                                 const void* __restrict__ z2raw, const float* __restrict__ Wzq,
                                                 const float* __restrict__ Wzk, const float* __restrict__ headw,
                                                 const int* __restrict__ flagp, short* __restrict__ Qb,
                                                 short* __restrict__ Kb, short* __restrict__ Vrow) {
  __shared__ float qt[8][16], kt[8][16], vt[8][24];
  const int bl = blockIdx.x, lane = threadIdx.x;
  const int h = lane >> 3, sub = lane & 7;
  const int flag = flagp[0];
  const float* pr = proj + (size_t)bl * NPROJ;
  const float* R = rotb + (size_t)bl * 9;
  const float txx = trans[bl * 3 + 0], tyy = trans[bl * 3 + 1], tzz = trans[bl * 3 + 2];
  float gamma;
  { const float w = headw[h]; gamma = (w > 20.f) ? w : log1pf(__expf(w)); }
  const float wL = 0.57735026918962576f;  // sqrt(1/3)
  const float wC = 0.23570226039551584f;  // sqrt(2/(9*4))
  const float ch = wL * wC * 0.5f * gamma;
  const float qscale = wL * 0.125f;       // wL / sqrt(64)

  // z-dot split across the 8 lanes of each h-group
  float zq0 = 0.f, zq1 = 0.f, zk0 = 0.f, zk1 = 0.f;
  const size_t zbase = (size_t)bl * 256;
  for (int zz = sub; zz < 128; zz += 8) {
    const float a0 = ldraw(z1raw, zbase + zz, flag);
    const float a1 = ldraw(z1raw, zbase + 128 + zz, flag);
    const float wq = Wzq[zz * 8 + h], wk = Wzk[zz * 8 + h];
    zq0 = fmaf(a0, wq, zq0); zq1 = fmaf(a1, wq, zq1);
    zk0 = fmaf(a0, wk, zk0); zk1 = fmaf(a1, wk, zk1);
  }
#pragma unroll
  for (int o = 1; o < 8; o <<= 1) {
    zq0 += __shfl_xor(zq0, o, 64); zq1 += __shfl_xor(zq1, o, 64);
    zk0 += __shfl_xor(zk0, o, 64); zk1 += __shfl_xor(zk1, o, 64);
  }

  const int b = bl >> 10, l = bl & 1023;
  const int bh = b * NH + h;
  const size_t row = (size_t)bh * LL + l;
  short* Q = Qb + row * QDP;
  short* Kx = Kb + row * QDP;
  short* Vo = Vrow + row * VDP;   // row-major, fully coalesced int4 stores

  // main 64 cols: each lane packs 8
  {
    const float* ps = pr + h * 64 + sub * 8;
    const float4 a0 = ((const float4*)ps)[0], a1 = ((const float4*)ps)[1];
    int4 qi;
    qi.x = packbf(a0.x * qscale, a0.y * qscale); qi.y = packbf(a0.z * qscale, a0.w * qscale);
    qi.z = packbf(a1.x * qscale, a1.y * qscale); qi.w = packbf(a1.z * qscale, a1.w * qscale);
    ((int4*)Q)[sub] = qi;
    const float* pk = pr + 512 + h * 64 + sub * 8;
    const float4 b0 = ((const float4*)pk)[0], b1 = ((const float4*)pk)[1];
    int4 ki;
    ki.x = packbf(b0.x, b0.y); ki.y = packbf(b0.z, b0.w);
    ki.z = packbf(b1.x, b1.y); ki.w = packbf(b1.z, b1.w);
    ((int4*)Kx)[sub] = ki;
    const float* pv = pr + 1024 + h * 64 + sub * 8;
    const float4 v0 = ((const float4*)pv)[0], v1 = ((const float4*)pv)[1];
    int4 vi;
    vi.x = packbf(v0.x, v0.y); vi.y = packbf(v0.z, v0.w);
    vi.z = packbf(v1.x, v1.y); vi.w = packbf(v1.z, v1.w);
    ((int4*)Vo)[sub] = vi;
  }

  // q/k points: lanes 0-3 -> q-points, 4-7 -> k-points
  {
    const float* pp = pr + ((sub < 4) ? 1536 : 1632) + h * 12 + (sub & 3) * 3;
    const float gx = R[0] * pp[0] + R[1] * pp[1] + R[2] * pp[2] + txx;
    const float gy = R[3] * pp[0] + R[4] * pp[1] + R[5] * pp[2] + tyy;
    const float gz = R[6] * pp[0] + R[7] * pp[1] + R[8] * pp[2] + tzz;
    float nrm = gx * gx + gy * gy + gz * gz;
    nrm += __shfl_xor(nrm, 1, 64);
    nrm += __shfl_xor(nrm, 2, 64);
    const float other = __shfl_xor(nrm, 4, 64);
    const float qn = (sub < 4) ? nrm : other;
    const float kn = (sub < 4) ? other : nrm;
    if (sub < 4) {
      qt[h][2 + sub * 3 + 0] = 2.f * ch * gx;
      qt[h][2 + sub * 3 + 1] = 2.f * ch * gy;
      qt[h][2 + sub * 3 + 2] = 2.f * ch * gz;
    } else {
      kt[h][2 + (sub - 4) * 3 + 0] = gx;
      kt[h][2 + (sub - 4) * 3 + 1] = gy;
      kt[h][2 + (sub - 4) * 3 + 2] = gz;
    }
    if (sub == 0) {
      qt[h][0] = wL * zq0; qt[h][1] = wL * zq1; qt[h][14] = -ch * qn; qt[h][15] = 1.f;
      kt[h][0] = zk0;      kt[h][1] = zk1;      kt[h][14] = 1.f;      kt[h][15] = -ch * kn;
    }
  }
  // V points -> vt LDS (cols 64..87)
  {
    const float* pv3 = pr + 1728 + h * 24 + sub * 3;
    const float gx = R[0] * pv3[0] + R[1] * pv3[1] + R[2] * pv3[2] + txx;
    const float gy = R[3] * pv3[0] + R[4] * pv3[1] + R[5] * pv3[2] + tyy;
    const float gz = R[6] * pv3[0] + R[7] * pv3[1] + R[8] * pv3[2] + tzz;
    vt[h][sub * 3 + 0] = gx; vt[h][sub * 3 + 1] = gy; vt[h][sub * 3 + 2] = gz;
  }
  // single wave: same-wave LDS RAW ordered by compiler waitcnt; pack tails
  {
    int4 z4; z4.x = 0; z4.y = 0; z4.z = 0; z4.w = 0;
    if (sub < 2) {
      const float* s4 = &qt[h][sub * 8];
      int4 qi;
      qi.x = packbf(s4[0], s4[1]); qi.y = packbf(s4[2], s4[3]);
      qi.z = packbf(s4[4], s4[5]); qi.w = packbf(s4[6], s4[7]);
      ((int4*)Q)[8 + sub] = qi;
    } else if (sub < 4) {
      const float* s4 = &kt[h][(sub - 2) * 8];
      int4 ki;
      ki.x = packbf(s4[0], s4[1]); ki.y = packbf(s4[2], s4[3]);
      ki.z = packbf(s4[4], s4[5]); ki.w = packbf(s4[6], s4[7]);
      ((int4*)Kx)[8 + sub - 2] = ki;
    } else if (sub == 4) ((int4*)Q)[10] = z4;
    else if (sub == 5) ((int4*)Q)[11] = z4;
    else if (sub == 6) ((int4*)Kx)[10] = z4;
    else ((int4*)Kx)[11] = z4;
    // V point tails: int4 #(8..10) from vt; V pad: int4 #19
    if (sub < 3) {
      const float* s4 = &vt[h][sub * 8];
      int4 vi;
      vi.x = packbf(s4[0], s4[1]); vi.y = packbf(s4[2], s4[3]);
      vi.z = packbf(s4[4], s4[5]); vi.w = packbf(s4[6], s4[7]);
      ((int4*)Vo)[8 + sub] = vi;
    } else if (sub == 3) {
      ((int4*)Vo)[19] = z4;
    }
  }
  // V z2 cols 88..151: int4 #(11+sub)
  {
    const size_t z2base = ((size_t)bl * NH + h) * 64 + sub * 8;
    float z[8];
#pragma unroll
    for (int e = 0; e < 8; e++) z[e] = ldraw(z2raw, z2base + e, flag);
    int4 vi;
    vi.x = packbf(z[0], z[1]); vi.y = packbf(z[2], z[3]);
    vi.z = packbf(z[4], z[5]); vi.w = packbf(z[6], z[7]);
    ((int4*)Vo)[11 + sub] = vi;
  }
}

// ---------- transpose V row-major [bh][L][160] -> V^T [bh][160][L] via LDS tile ----------
__global__ __launch_bounds__(256) void vtrans_k(const short* __restrict__ Vrow, short* __restrict__ Vtb) {
  __shared__ __align__(16) short T[64 * 168];
  const int tid = threadIdx.x;
  const int bh = blockIdx.y;
  const int l0 = blockIdx.x * 64;
  const short* src = Vrow + (size_t)bh * LL * VDP + (size_t)l0 * VDP;
  for (int u = tid; u < 1280; u += 256) {
    const int ll = u / 20, j = u % 20;
    *(int4*)&T[ll * 168 + j * 8] = *(const int4*)(src + (size_t)ll * VDP + j * 8);
  }
  __syncthreads();
  short* dst = Vtb + (size_t)bh * VDP * LL + l0;
  for (int u = tid; u < 1280; u += 256) {
    const int c = u >> 3, seg = u & 7;
    short tmp[8];
#pragma unroll
    for (int e = 0; e < 8; e++) tmp[e] = T[(seg * 8 + e) * 168 + c];
    *(int4*)(dst + (size_t)c * LL + seg * 8) = *(const int4*)tmp;
  }
}

// ---------- MFMA flash attention v3: 8 waves, j-split halves, register prefetch pipeline ----------
// launch_bounds(512, 2): grid is 512 blocks on 256 CUs -> 2 blocks/CU is the grid-imposed cap,
// so the 128-VGPR budget costs no occupancy (the (512,4)/64-VGPR bound caused scratch spills).
__global__ __launch_bounds__(512, 2) void attn_k(const short* __restrict__ Qb, const short* __restrict__ Kb,
                                                 const short* __restrict__ Vtb, const float* __restrict__ maskF,
                                                 float* __restrict__ Oext) {
  __shared__ __align__(16) short smem[26624];   // 53,248 B
  short* Ks = smem;                    // [2][32][104]
  short* Vs = smem + 6656;             // [2][160][40]
  short* Ps = smem + 19456;            // [8][16][40]
  float* Msl = (float*)(smem + 24576); // [1024] full mask row
  const int tid = threadIdx.x;
  const int wid = tid >> 6, lane = tid & 63;
  const int c15 = lane & 15, q = lane >> 4;
  const int blk = blockIdx.x;
  const int bh = blk & 31, qt2 = blk >> 5;      // same-bh blocks share blk%8 -> same XCD
  const int b = bh >> 3, h = bh & 7;
  const int half = wid >> 2, mw = wid & 3;
  const int i0 = qt2 * 64 + mw * 16;

  const short* Kbase = Kb + (size_t)bh * LL * QDP;
  const short* Vbase = Vtb + (size_t)bh * VDP * LL;

  s8v Qa[3];
  const short* Qrow = Qb + ((size_t)bh * LL + i0 + c15) * QDP;
#pragma unroll
  for (int kc = 0; kc < 3; kc++) Qa[kc] = *(const s8v*)(Qrow + kc * 32 + q * 8);

  f4v Of[10];
#pragma unroll
  for (int vt = 0; vt < 10; vt++) Of[vt] = (f4v){0.f, 0.f, 0.f, 0.f};
  float mold[4] = {-1e30f, -1e30f, -1e30f, -1e30f};
  float lsum[4] = {0.f, 0.f, 0.f, 0.f};

  // mask preload (whole row)
  Msl[tid] = maskF[b * LL + tid];
  Msl[tid + 512] = maskF[b * LL + tid + 512];

  // staging index decomposition (fixed per thread)
  const int khs0 = tid / 384;
  const int kv0 = tid - khs0 * 384;
  const int krr0 = kv0 / 12, kcc0 = kv0 - krr0 * 12;
  int khs1 = 0, krr1 = 0, kcc1 = 0;
  if (tid < 256) { const int u = tid + 512; khs1 = u / 384; const int v2 = u - khs1 * 384; krr1 = v2 / 12; kcc1 = v2 - krr1 * 12; }
  const int vhs0 = tid / 640; const int vv0 = tid - vhs0 * 640; const int vcc0 = vv0 >> 2, vp0 = vv0 & 3;
  const int vhs1 = (tid + 512) / 640; const int vv1 = (tid + 512) - vhs1 * 640; const int vcc1 = vv1 >> 2, vp1 = vv1 & 3;
  int vhs2 = 0, vcc2 = 0, vp2 = 0;
  if (tid < 256) { const int u = tid + 1024; vhs2 = u / 640; const int v2 = u - vhs2 * 640; vcc2 = v2 >> 2; vp2 = v2 & 3; }

  // prefetch tile 0
  int4 kr0, kr1, vr0, vr1, vr2;
  kr0 = *(const int4*)(Kbase + (size_t)(khs0 * 512 + krr0) * QDP + kcc0 * 8);
  if (tid < 256) kr1 = *(const int4*)(Kbase + (size_t)(khs1 * 512 + krr1) * QDP + kcc1 * 8);
  vr0 = *(const int4*)(Vbase + (size_t)vcc0 * LL + vhs0 * 512 + vp0 * 8);
  vr1 = *(const int4*)(Vbase + (size_t)vcc1 * LL + vhs1 * 512 + vp1 * 8);
  if (tid < 256) vr2 = *(const int4*)(Vbase + (size_t)vcc2 * LL + vhs2 * 512 + vp2 * 8);

  short* Ksl = Ks + half * 3328;
  short* Vsl = Vs + half * 6400;
  short* Pl = Ps + wid * 640;

  for (int jt = 0; jt < 16; jt++) {
    const int j0 = jt * 32;
    __syncthreads();   // prior compute done (jt=0: also orders Msl writes)
    *(int4*)&Ks[khs0 * 3328 + krr0 * 104 + kcc0 * 8] = kr0;
    if (tid < 256) *(int4*)&Ks[khs1 * 3328 + krr1 * 104 + kcc1 * 8] = kr1;
    *(int4*)&Vs[vhs0 * 6400 + vcc0 * 40 + vp0 * 8] = vr0;
    *(int4*)&Vs[vhs1 * 6400 + vcc1 * 40 + vp1 * 8] = vr1;
    if (tid < 256) *(int4*)&Vs[vhs2 * 6400 + vcc2 * 40 + vp2 * 8] = vr2;
    __syncthreads();
    if (jt < 15) {     // prefetch next tile into registers (overlaps compute)
      const int j0n = j0 + 32;
      kr0 = *(const int4*)(Kbase + (size_t)(khs0 * 512 + j0n + krr0) * QDP + kcc0 * 8);
      if (tid < 256) kr1 = *(const int4*)(Kbase + (size_t)(khs1 * 512 + j0n + krr1) * QDP + kcc1 * 8);
      vr0 = *(const int4*)(Vbase + (size_t)vcc0 * LL + vhs0 * 512 + j0n + vp0 * 8);
      vr1 = *(const int4*)(Vbase + (size_t)vcc1 * LL + vhs1 * 512 + j0n + vp1 * 8);
      if (tid < 256) vr2 = *(const int4*)(Vbase + (size_t)vcc2 * LL + vhs2 * 512 + j0n + vp2 * 8);
    }

    f4v Sf0 = (f4v){0.f, 0.f, 0.f, 0.f}, Sf1 = (f4v){0.f, 0.f, 0.f, 0.f};
#pragma unroll
    for (int kc = 0; kc < 3; kc++) {
      const s8v K0 = *(const s8v*)&Ksl[c15 * 104 + kc * 32 + q * 8];
      const s8v K1 = *(const s8v*)&Ksl[(16 + c15) * 104 + kc * 32 + q * 8];
      Sf0 = __builtin_amdgcn_mfma_f32_16x16x32_bf16(Qa[kc], K0, Sf0, 0, 0, 0);
      Sf1 = __builtin_amdgcn_mfma_f32_16x16x32_bf16(Qa[kc], K1, Sf1, 0, 0, 0);
    }
    const float mv0 = Msl[half * 512 + j0 + c15];
    const float mv1 = Msl[half * 512 + j0 + 16 + c15];
    float lg0[4], lg1[4], tm[4], p0[4], p1[4];
#pragma unroll
    for (int r = 0; r < 4; r++) {
      lg0[r] = (mv0 > 0.f) ? Sf0[r] : -1e9f;
      lg1[r] = (mv1 > 0.f) ? Sf1[r] : -1e9f;
      tm[r] = fmaxf(lg0[r], lg1[r]);
    }
#pragma unroll
    for (int r = 0; r < 4; r++) {
      tm[r] = fmaxf(tm[r], __shfl_xor(tm[r], 1, 64));
      tm[r] = fmaxf(tm[r], __shfl_xor(tm[r], 2, 64));
      tm[r] = fmaxf(tm[r], __shfl_xor(tm[r], 4, 64));
      tm[r] = fmaxf(tm[r], __shfl_xor(tm[r], 8, 64));
    }
    const bool need = (tm[0] > mold[0]) | (tm[1] > mold[1]) | (tm[2] > mold[2]) | (tm[3] > mold[3]);
    if (__any(need)) {
      float al[4];
#pragma unroll
      for (int r = 0; r < 4; r++) {
        const float mn = fmaxf(mold[r], tm[r]);
        al[r] = __expf(mold[r] - mn);
        mold[r] = mn;
        p0[r] = __expf(lg0[r] - mn);
        p1[r] = __expf(lg1[r] - mn);
        lsum[r] = lsum[r] * al[r] + p0[r] + p1[r];
      }
#pragma unroll
      for (int vt = 0; vt < 10; vt++) {
#pragma unroll
        for (int r = 0; r < 4; r++) Of[vt][r] *= al[r];
      }
    } else {
#pragma unroll
      for (int r = 0; r < 4; r++) {
        p0[r] = __expf(lg0[r] - mold[r]);
        p1[r] = __expf(lg1[r] - mold[r]);
        lsum[r] += p0[r] + p1[r];
      }
    }
#pragma unroll
    for (int r = 0; r < 4; r++) {
      Pl[(q * 4 + r) * 40 + c15] = f2bs(p0[r]);
      Pl[(q * 4 + r) * 40 + 16 + c15] = f2bs(p1[r]);
    }
    const s8v Pa = *(const s8v*)&Pl[c15 * 40 + q * 8];
#pragma unroll
    for (int vt = 0; vt < 10; vt++) {
      const s8v Vf = *(const s8v*)&Vsl[(vt * 16 + c15) * 40 + q * 8];
      Of[vt] = __builtin_amdgcn_mfma_f32_16x16x32_bf16(Pa, Vf, Of[vt], 0, 0, 0);
    }
  }
#pragma unroll
  for (int r = 0; r < 4; r++) {
    lsum[r] += __shfl_xor(lsum[r], 1, 64);
    lsum[r] += __shfl_xor(lsum[r], 2, 64);
    lsum[r] += __shfl_xor(lsum[r], 4, 64);
    lsum[r] += __shfl_xor(lsum[r], 8, 64);
  }
  // merge halves through LDS
  float* Obuf = (float*)smem;              // [4][16][160] = 40,960 B
  float* Mbuf = (float*)(smem + 20480);    // [64]
  float* Lbuf = Mbuf + 64;                 // [64]
  __syncthreads();
  if (half == 1) {
#pragma unroll
    for (int r = 0; r < 4; r++) {
      const int rowi = mw * 16 + q * 4 + r;
#pragma unroll
      for (int vt = 0; vt < 10; vt++) Obuf[rowi * 160 + vt * 16 + c15] = Of[vt][r];
      if (c15 == 0) { Mbuf[rowi] = mold[r]; Lbuf[rowi] = lsum[r]; }
    }
  }
  __syncthreads();
  if (half == 0) {
#pragma unroll
    for (int r = 0; r < 4; r++) {
      const int rowi = mw * 16 + q * 4 + r;
      const float m2 = Mbuf[rowi], l2 = Lbuf[rowi];
      const float mx = fmaxf(mold[r], m2);
      const float a1 = __expf(mold[r] - mx), a2 = __expf(m2 - mx);
      const float inv = 1.f / (lsum[r] * a1 + l2 * a2);
      const int i = i0 + q * 4 + r;
      float* Or = Oext + ((size_t)(b * LL + i) * NH + h) * VDP;
#pragma unroll
      for (int vt = 0; vt < 10; vt++)
        Or[vt * 16 + c15] = (Of[vt][r] * a1 + Obuf[rowi * 160 + vt * 16 + c15] * a2) * inv;
    }
  }
}

// ---------- feat assembly (wave per residue) ----------
__global__ __launch_bounds__(64) void feat_k(const float* __restrict__ Oext, const float* __restrict__ rotb,
                                             const float* __restrict__ trans, float* __restrict__ feat) {
  const int bl = blockIdx.x, lane = threadIdx.x;
  const int h = lane >> 3, sub = lane & 7;
  const float* O = Oext + ((size_t)bl * 8 + h) * VDP;
  float* f = feat + (size_t)bl * FEATD;
  {
    const float4 a0 = ((const float4*)(O + sub * 8))[0], a1 = ((const float4*)(O + sub * 8))[1];
    ((float4*)(f + h * 64 + sub * 8))[0] = a0;
    ((float4*)(f + h * 64 + sub * 8))[1] = a1;
    const float4 z0 = ((const float4*)(O + 88 + sub * 8))[0], z1 = ((const float4*)(O + 88 + sub * 8))[1];
    ((float4*)(f + 768 + h * 64 + sub * 8))[0] = z0;
    ((float4*)(f + 768 + h * 64 + sub * 8))[1] = z1;
  }
  const float* R = rotb + (size_t)bl * 9;
  const float txx = trans[bl * 3 + 0], tyy = trans[bl * 3 + 1], tzz = trans[bl * 3 + 2];
  {
    const float dx = O[64 + sub * 3 + 0] - txx;
    const float dy = O[64 + sub * 3 + 1] - tyy;
    const float dz = O[64 + sub * 3 + 2] - tzz;
    const float lx = R[0] * dx + R[3] * dy + R[6] * dz;   // R^T * diff
    const float ly = R[1] * dx + R[4] * dy + R[7] * dz;
    const float lz = R[2] * dx + R[5] * dy + R[8] * dz;
    f[512 + h * 24 + sub * 3 + 0] = lx;
    f[512 + h * 24 + sub * 3 + 1] = ly;
    f[512 + h * 24 + sub * 3 + 2] = lz;
    f[704 + h * 8 + sub] = sqrtf(lx * lx + ly * ly + lz * lz + 1e-8f);
  }
}

// ---------- LayerNorm(x + resid) (one wave per row) ----------
__global__ __launch_bounds__(64) void ln_k(const float* __restrict__ x, const float* __restrict__ resid,
                                           const float* __restrict__ g, const float* __restrict__ bta,
                                           float* __restrict__ out) {
  const int row = blockIdx.x, t = threadIdx.x;
  const float* xr = x + (size_t)row * CSD;
  const float* rr = resid + (size_t)row * CSD;
  float v[6];
  float s = 0.f;
#pragma unroll
  for (int e = 0; e < 6; e++) {
    const int c = t + e * 64;
    v[e] = xr[c] + rr[c];
    s += v[e];
  }
  s = wredf(s);
  const float mu = s * (1.f / 384.f);
  float var = 0.f;
#pragma unroll
  for (int e = 0; e < 6; e++) { const float d = v[e] - mu; var = fmaf(d, d, var); }
  var = wredf(var) * (1.f / 384.f);
  const float inv = rsqrtf(var + 1e-5f);
#pragma unroll
  for (int e = 0; e < 6; e++) {
    const int c = t + e * 64;
    out[(size_t)row * CSD + c] = (v[e] - mu) * inv * g[c] + bta[c];
  }
}

// ---------- fused tail LN + backbone update + mHC combine ----------
__global__ __launch_bounds__(64) void lnfinal_k(const float* __restrict__ x /*x3*/, const float* __restrict__ resid /*s1*/,
                                                const float* __restrict__ g, const float* __restrict__ bta,
                                                const float* __restrict__ sF, const float* __restrict__ rotb,
                                                const float* __restrict__ trans, const float* __restrict__ hpost,
                                                const float* __restrict__ rowsum, const float* __restrict__ Wbb,
                                                const float* __restrict__ bbb, const int* __restrict__ flagp,
                                                void* __restrict__ outv) {
  const int bl = blockIdx.x, t = threadIdx.x;
  const int flag = flagp[0];
  bf16* outb = (bf16*)outv;
  float* outf = (float*)outv;
  // --- LN(x + resid) -> si values in registers ---
  const float* xr = x + (size_t)bl * CSD;
  const float* rr = resid + (size_t)bl * CSD;
  float v[6];
  float s = 0.f;
#pragma unroll
  for (int e = 0; e < 6; e++) {
    const int c = t + e * 64;
    v[e] = xr[c] + rr[c];
    s += v[e];
  }
  s = wredf(s);
  const float mu = s * (1.f / 384.f);
  float var = 0.f;
#pragma unroll
  for (int e = 0; e < 6; e++) { const float d = v[e] - mu; var = fmaf(d, d, var); }
  var = wredf(var) * (1.f / 384.f);
  const float inv = rsqrtf(var + 1e-5f);
  float si6[6];
#pragma unroll
  for (int e = 0; e < 6; e++) {
    const int c = t + e * 64;
    si6[e] = (v[e] - mu) * inv * g[c] + bta[c];
  }
  // --- backbone update ---
  float d6[6] = {0.f, 0.f, 0.f, 0.f, 0.f, 0.f};
#pragma unroll
  for (int e = 0; e < 6; e++) {
    const int c = t + e * 64;
#pragma unroll
    for (int u = 0; u < 6; u++) d6[u] = fmaf(si6[e], Wbb[c * 6 + u], d6[u]);
  }
#pragma unroll
  for (int u = 0; u < 6; u++) d6[u] = wredf(d6[u]);
  float upd[6];
#pragma unroll
  for (int u = 0; u < 6; u++) upd[u] = d6[u] + bbb[u];
  const float* R = rotb + (size_t)bl * 9;
  if (t == 0) {
    float w = 1.f, x2 = upd[0], y = upd[1], z = upd[2];
    const float iq = rsqrtf(w * w + x2 * x2 + y * y + z * z + 1e-8f);
    w *= iq; x2 *= iq; y *= iq; z *= iq;
    const float Ru[9] = {1.f - 2.f * (y * y + z * z), 2.f * (x2 * y - w * z), 2.f * (x2 * z + w * y),
                         2.f * (x2 * y + w * z), 1.f - 2.f * (x2 * x2 + z * z), 2.f * (y * z - w * x2),
                         2.f * (x2 * z - w * y), 2.f * (y * z + w * x2), 1.f - 2.f * (x2 * x2 + y * y)};
#pragma unroll
    for (int i = 0; i < 3; i++)
#pragma unroll
      for (int j = 0; j < 3; j++) {
        const float rv = R[i * 3 + 0] * Ru[0 + j] + R[i * 3 + 1] * Ru[3 + j] + R[i * 3 + 2] * Ru[6 + j];
        const size_t o = OUT_ROT + (size_t)bl * 9 + i * 3 + j;
        if (flag) outb[o] = __float2bfloat16(rv); else outf[o] = rv;
      }
#pragma unroll
    for (int i = 0; i < 3; i++) {
      const float tv = R[i * 3 + 0] * upd[3] + R[i * 3 + 1] * upd[4] + R[i * 3 + 2] * upd[5] + trans[bl * 3 + i];
      const size_t o = OUT_TR + (size_t)bl * 3 + i;
      if (flag) outb[o] = __float2bfloat16(tv); else outf[o] = tv;
    }
  }
  // --- mHC combine ---
  const float hp0 = hpost[bl * 4 + 0], hp1 = hpost[bl * 4 + 1], hp2 = hpost[bl * 4 + 2], hp3 = hpost[bl * 4 + 3];
  const float rs0 = rowsum[bl * 4 + 0], rs1 = rowsum[bl * 4 + 1], rs2 = rowsum[bl * 4 + 2], rs3 = rowsum[bl * 4 + 3];
  const float* sr = sF + (size_t)bl * CSD;
#pragma unroll
  for (int e = 0; e < 6; e++) {
    const int c = t + e * 64;
    const float sv = sr[c], sp = si6[e];
    const size_t base = (size_t)bl * 4 * CSD + c;
    const float o0 = rs0 * sv + hp0 * sp;
    const float o1 = rs1 * sv + hp1 * sp;
    const float o2 = rs2 * sv + hp2 * sp;
    const float o3 = rs3 * sv + hp3 * sp;
    if (flag) {
      outb[base + 0 * CSD] = __float2bfloat16(o0);
      outb[base + 1 * CSD] = __float2bfloat16(o1);
      outb[base + 2 * CSD] = __float2bfloat16(o2);
      outb[base + 3 * CSD] = __float2bfloat16(o3);
    } else {
      outf[base + 0 * CSD] = o0;
      outf[base + 1 * CSD] = o1;
      outf[base + 2 * CSD] = o2;
      outf[base + 3 * CSD] = o3;
    }
  }
}

extern "C" void kernel_launch(void* const* d_in, const int* in_sizes, int n_in,
                              void* d_out, int out_size, void* d_ws, size_t ws_size,
                              hipStream_t stream) {
  float* ws = (float*)d_ws;
  int* flag = (int*)(ws + WS_FLAG);

  P36 ptrs;
  for (int i = 0; i < 36; i++) ptrs.p[i] = d_in[i];

  float* sF     = ws + OFF_S;
  float* WpostR = ws + WS_WPOSTR;
  float* WresR  = ws + WS_WRESR;
  float* hpost  = ws + WS_HPOST;
  float* rowsum = ws + WS_ROWSUM;
  float* rotb   = ws + WS_ROTB;
  short* WcatT  = (short*)(ws + WS_WCATT);
  short* WoT    = (short*)(ws + WS_WOT);
  short* Wt1T   = (short*)(ws + WS_WT1T);
  short* Wt2T   = (short*)(ws + WS_WT2T);
  short* Wt3T   = (short*)(ws + WS_WT3T);
  float* proj   = ws + WS_PROJ;
  short* Qb     = (short*)(ws + WS_QB);
  short* Kb     = (short*)(ws + WS_KB);
  short* Vtb    = (short*)(ws + WS_VT);
  short* Vrow   = (short*)(ws + WS_VROW);
  float* Oext   = ws + WS_PROJ;               // overlay (proj dead after assemble)
  float* featb  = ws + WS_QB;                 // overlay, spans QB..VT (dead after attn)
  float* x1s1   = ws + WS_PROJ;               // overlay (Oext dead after feat_k)
  float* t1b    = ws + WS_PROJ + 1572864;
  float* t2b    = ws + WS_PROJ + 3145728;
  float* x3     = ws + WS_PROJ + 4718592;

  detect_k<<<1, 64, 0, stream>>>((const unsigned int*)d_in[5], flag);
  cvtall_k<<<(IN_END + 255) / 256, 256, 0, stream>>>(ptrs, ws, flag);
  wprep_k<<<1632, 256, 0, stream>>>(ws, (short*)ws);
  wreduce_k<<<24, 256, 0, stream>>>(ws + OFF_WPOST, ws + OFF_WRES, WpostR, WresR);
  mhc_k<<<BL, 64, 0, stream>>>(sF, ws + OFF_QUAT, ws + OFF_BPOST, ws + OFF_BRES, ws + OFF_ALPHA,
                               WpostR, WresR, hpost, rowsum, rotb);
  gemm_mfma_k<<<dim3(15, 32), 256, 0, stream>>>(sF, WcatT, nullptr, proj, BL, NPROJ, CSD, 0);
  assemble_k<<<BL, 64, 0, stream>>>(proj, rotb, ws + OFF_TRANS, d_in[1], d_in[2],
                                    ws + OFF_WZQ, ws + OFF_WZK, ws + OFF_HEADW, flag, Qb, Kb, Vrow);
  vtrans_k<<<dim3(16, 32), 256, 0, stream>>>(Vrow, Vtb);
  attn_k<<<512, 512, 0, stream>>>(Qb, Kb, Vtb, ws + OFF_MASK, Oext);
  feat_k<<<BL, 64, 0, stream>>>(Oext, rotb, ws + OFF_TRANS, featb);
  gemm_mfma_k<<<dim3(3, 32), 256, 0, stream>>>(featb, WoT, ws + OFF_BO, x1s1, BL, CSD, FEATD, 0);
  ln_k<<<BL, 64, 0, stream>>>(x1s1, sF, ws + OFF_LN1G, ws + OFF_LN1B, x1s1);                   // s1
  gemm_mfma_k<<<dim3(3, 32), 256, 0, stream>>>(x1s1, Wt1T, ws + OFF_BT1, t1b, BL, CSD, CSD, 1);
  gemm_mfma_k<<<dim3(3, 32), 256, 0, stream>>>(t1b, Wt2T, ws + OFF_BT2, t2b, BL, CSD, CSD, 1);
  gemm_mfma_k<<<dim3(3, 32), 256, 0, stream>>>(t2b, Wt3T, ws + OFF_BT3, x3, BL, CSD, CSD, 0);
  lnfinal_k<<<BL, 64, 0, stream>>>(x3, x1s1, ws + OFF_LNTG, ws + OFF_LNTB, sF, rotb,
                                   ws + OFF_TRANS, hpost, rowsum, ws + OFF_WBB, ws + OFF_BBB,
                                   flag, d_out);
}